// Round 13
// baseline (716.025 us; speedup 1.0000x reference)
//
#include <hip/hip_runtime.h>
#include <cstdint>

#define BN_EPS 1e-5f

typedef _Float16 f16x8 __attribute__((ext_vector_type(8)));
typedef _Float16 f16x2 __attribute__((ext_vector_type(2)));
typedef float f32x4 __attribute__((ext_vector_type(4)));

__device__ __forceinline__ unsigned short f2h(float f) {
  _Float16 h = (_Float16)f;
  return *(unsigned short*)&h;
}
__device__ __forceinline__ float2 h2f2(unsigned int q) {
  f16x2 h = __builtin_bit_cast(f16x2, q);
  return make_float2((float)h.x, (float)h.y);
}

// ---------------------------------------------------------------------------
// CSR build (by dst), once per call — bucket-first, no per-node atomics.
// ---------------------------------------------------------------------------
#define CHUNK 8192
#define MAXBUK 512

__global__ __launch_bounds__(256) void k_bcount(const int* __restrict__ dst, int* __restrict__ bcnt, int E) {
  __shared__ int hist[MAXBUK];
  int tid = threadIdx.x;
  int base = blockIdx.x * CHUNK;
  int cnt = min(CHUNK, E - base);
  if (cnt <= 0) return;
  for (int b = tid; b < MAXBUK; b += 256) hist[b] = 0;
  __syncthreads();
  for (int i = tid; i < cnt; i += 256) atomicAdd(&hist[dst[base + i] >> 7], 1);
  __syncthreads();
  for (int b = tid; b < MAXBUK; b += 256) {
    int c = hist[b];
    if (c > 0) atomicAdd(&bcnt[b], c);
  }
}

__global__ __launch_bounds__(512) void k_bscan(const int* __restrict__ bcnt, int* __restrict__ bcur,
                                               int* __restrict__ bbase, int nbuk) {
  __shared__ int sh[512];
  int t = threadIdx.x;
  int v = (t < nbuk) ? bcnt[t] : 0;
  sh[t] = v;
  __syncthreads();
  for (int off = 1; off < 512; off <<= 1) {
    int u = (t >= off) ? sh[t - off] : 0;
    __syncthreads();
    sh[t] += u;
    __syncthreads();
  }
  if (t < nbuk) {
    int excl = sh[t] - v;
    bcur[t] = excl;
    bbase[t] = excl;
  }
}

__global__ __launch_bounds__(256) void k_bucket(const int* __restrict__ src, const int* __restrict__ dst,
                                                int* __restrict__ bcur, unsigned int* __restrict__ pairs,
                                                int E) {
  __shared__ unsigned int ep[CHUNK];
  __shared__ int bcnt[MAXBUK];
  __shared__ int gbase[MAXBUK];
  __shared__ int rcnt[MAXBUK];
  int tid = threadIdx.x;
  int base = blockIdx.x * CHUNK;
  int cnt = min(CHUNK, E - base);
  if (cnt <= 0) return;

  for (int b = tid; b < MAXBUK; b += 256) { bcnt[b] = 0; rcnt[b] = 0; }
  __syncthreads();
  for (int i = tid; i < cnt; i += 256) {
    int d = dst[base + i];
    int s = src[base + i];
    unsigned int pk = ((unsigned)(d >> 7) << 23) | ((unsigned)(d & 127) << 16) | (unsigned)s;
    ep[i] = pk;
    atomicAdd(&bcnt[d >> 7], 1);
  }
  __syncthreads();
  for (int b = tid; b < MAXBUK; b += 256) {
    int c = bcnt[b];
    gbase[b] = (c > 0) ? atomicAdd(&bcur[b], c) : 0;
  }
  __syncthreads();
  for (int i = tid; i < cnt; i += 256) {
    unsigned int pk = ep[i];
    int bk = pk >> 23;
    int r = atomicAdd(&rcnt[bk], 1);
    pairs[gbase[bk] + r] = pk & 0x007FFFFFu;
  }
}

#define PLACE_CAP 24576

__global__ __launch_bounds__(256) void k_place(const int* __restrict__ bbase,
                                               const unsigned int* __restrict__ pairs,
                                               unsigned short* __restrict__ csr16,
                                               int* __restrict__ rowptr, int n, int nbuk, int E) {
  __shared__ unsigned short stage[PLACE_CAP];
  __shared__ int nc[128];
  __shared__ int nstart[128];
  __shared__ int nrun[128];
  int tid = threadIdx.x;
  int bk = blockIdx.x;
  int v0 = bk * 128;
  int beg = bbase[bk];
  int end = (bk + 1 < nbuk) ? bbase[bk + 1] : E;
  int cnt = end - beg;
  if (tid < 128) { nc[tid] = 0; nrun[tid] = 0; }
  __syncthreads();
  for (int i = tid; i < cnt; i += 256) atomicAdd(&nc[(pairs[beg + i] >> 16) & 127], 1);
  __syncthreads();
  if (tid < 128) nstart[tid] = nc[tid];
  __syncthreads();
  for (int off = 1; off < 128; off <<= 1) {
    int v = (tid < 128 && tid >= off) ? nstart[tid - off] : 0;
    __syncthreads();
    if (tid < 128) nstart[tid] += v;
    __syncthreads();
  }
  if (tid < 128) nstart[tid] -= nc[tid];
  __syncthreads();
  if (tid < 128 && v0 + tid < n) rowptr[v0 + tid] = beg + nstart[tid];
  if (bk == nbuk - 1 && tid == 0) rowptr[n] = E;
  if (cnt <= 0) return;
  if (cnt <= PLACE_CAP) {
    for (int i = tid; i < cnt; i += 256) {
      unsigned int p = pairs[beg + i];
      int dlow = (p >> 16) & 127;
      int r = atomicAdd(&nrun[dlow], 1);
      stage[nstart[dlow] + r] = (unsigned short)(p & 0xFFFF);
    }
    __syncthreads();
    for (int i = tid; i < cnt; i += 256) csr16[beg + i] = stage[i];
  } else {
    for (int i = tid; i < cnt; i += 256) {
      unsigned int p = pairs[beg + i];
      int dlow = (p >> 16) & 127;
      int r = atomicAdd(&nrun[dlow], 1);
      csr16[beg + nstart[dlow] + r] = (unsigned short)(p & 0xFFFF);
    }
  }
}

// ---------------------------------------------------------------------------
// one-shot fp32 -> fp16 conversion of all static weights (per call).
// ff_w2 rows padded 218 -> 224 halves (zero fill).
// ---------------------------------------------------------------------------
__global__ __launch_bounds__(256) void k_cvtw(
    const float* __restrict__ emb, const float* __restrict__ fc,
    const float* __restrict__ w2, const float* __restrict__ mlp,
    unsigned short* __restrict__ o_emb, unsigned short* __restrict__ o_fc,
    unsigned short* __restrict__ o_w2, unsigned short* __restrict__ o_mlp,
    int n_emb, int n_fc, int n_w2rows, int n_mlp) {
  int idx = blockIdx.x * 256 + threadIdx.x;
  if (idx < n_emb) { o_emb[idx] = f2h(emb[idx]); return; }
  idx -= n_emb;
  if (idx < n_fc) { o_fc[idx] = f2h(fc[idx]); return; }
  idx -= n_fc;
  int w2tot = n_w2rows * 224;
  if (idx < w2tot) {
    int r = idx / 224, c = idx - r * 224;
    o_w2[idx] = f2h((c < 218) ? w2[r * 218 + c] : 0.f);
    return;
  }
  idx -= w2tot;
  if (idx < n_mlp) o_mlp[idx] = f2h(mlp[idx]);
}

// ---------------------------------------------------------------------------
// fold bn1 affine into ff1 weights (per layer, after bn1 stats).
// ---------------------------------------------------------------------------
__global__ __launch_bounds__(256) void k_foldw1(const float* __restrict__ W1, const float* __restrict__ b1,
                                                const float* __restrict__ stats, const float* __restrict__ gam,
                                                const float* __restrict__ bet, float invM,
                                                unsigned short* __restrict__ W16, float* __restrict__ b1p,
                                                int rows, int K) {
  __shared__ float aA[128];
  __shared__ float aB[128];
  int tid = threadIdx.x;
  if (tid < K) {
    float mean = stats[tid] * invM;
    float var = stats[K + tid] * invM - mean * mean;
    float a = gam[tid] * rsqrtf(var + BN_EPS);
    aA[tid] = a;
    aB[tid] = bet[tid] - mean * a;
  }
  __syncthreads();
  int w = tid >> 6, lane = tid & 63;
  int i = blockIdx.x * 4 + w;
  if (i >= rows) return;
  const float* wr = W1 + (size_t)i * K;
  float dot = 0.f;
  for (int k = lane; k < K; k += 64) {
    float wv = wr[k];
    W16[(size_t)i * K + k] = f2h(wv * aA[k]);
    dot += wv * aB[k];
  }
  for (int o = 32; o > 0; o >>= 1) dot += __shfl_down(dot, o, 64);
  if (lane == 0) b1p[i] = b1[i] + dot;
}

// ---------------------------------------------------------------------------
// fp16-MFMA GEMM, templated on column-tile count NCT (64*NCT/16 cols/block).
// flags: bit0 relu | bit1 input BN affine (fp32 X only) | bit2 Y fp16 |
//        bit3 X fp16 | bit4 fused col-stats (NCT=4, COLS<=64, grid.y=1) |
//        bit5 fused attn logits (NCT=8, COLS=128, 2 heads/block) | bit6 W fp16
// xsout != nullptr: side-write the affined fp16 X tile to xsout (pitch 256)
// — fuses the previous layer's bn2-apply into this GEMM's staging (KK==64).
// ---------------------------------------------------------------------------
template <int NCT>
__global__ __launch_bounds__(256) void k_gemm(
    const void* __restrict__ Xv, int xpitch,
    const void* __restrict__ Wv, int wpitch,
    const float* __restrict__ bias,
    const float* __restrict__ stats, const float* __restrict__ gamma, const float* __restrict__ beta,
    float invM, void* __restrict__ Yv, int ypitch,
    int M, int KK, int COLS, int flags,
    float* __restrict__ ostats,
    const float* __restrict__ al, const float* __restrict__ ar,
    float* __restrict__ el, float* __restrict__ er,
    unsigned short* __restrict__ xsout) {
  __shared__ unsigned short Xs[128 * 72];
  __shared__ unsigned short Ws[NCT * 16 * 72];
  __shared__ float affA[256];
  __shared__ float affB[256];

  int tid = threadIdx.x;
  int m0 = blockIdx.x * 128;
  int c0 = blockIdx.y * (NCT * 16);
  const bool relu = (flags & 1) != 0;
  const bool aff = (flags & 2) != 0;
  const bool yf16 = (flags & 4) != 0;
  const bool xf16 = (flags & 8) != 0;
  const bool fstat = (flags & 16) != 0;
  const bool fattn = (flags & 32) != 0;
  const bool wf16 = (flags & 64) != 0;

  if (aff) {
    if (tid < KK && tid < 256) {
      float mean = stats[tid] * invM;
      float var = stats[KK + tid] * invM - mean * mean;
      float a = gamma[tid] * rsqrtf(var + BN_EPS);
      affA[tid] = a;
      affB[tid] = beta[tid] - mean * a;
    }
    __syncthreads();
  }

  int w = tid >> 6;
  int lane = tid & 63;
  int l15 = lane & 15;
  int lhi = lane >> 4;

  f32x4 acc[2][NCT];
#pragma unroll
  for (int i = 0; i < 2; ++i)
#pragma unroll
    for (int j = 0; j < NCT; ++j) acc[i][j] = (f32x4){0.f, 0.f, 0.f, 0.f};

  for (int kt = 0; kt < KK; kt += 64) {
    // ---- stage X tile (128 x 64 halves)
    if (xf16) {
      const unsigned short* X16 = (const unsigned short*)Xv;
#pragma unroll
      for (int p = 0; p < 4; ++p) {
        int idx = p * 256 + tid;
        int r = idx >> 3;
        int k8 = (idx & 7) * 8;
        int gr = m0 + r, gk = kt + k8;
        if (gr < M && gk + 8 <= KK) {
          *(uint4*)&Xs[r * 72 + k8] = *(const uint4*)(X16 + (size_t)gr * xpitch + gk);
        } else {
#pragma unroll
          for (int j = 0; j < 8; ++j)
            Xs[r * 72 + k8 + j] =
                (gr < M && gk + j < KK) ? X16[(size_t)gr * xpitch + gk + j] : (unsigned short)0;
        }
      }
    } else {
      const float* X = (const float*)Xv;
      int rb = tid >> 4;
      int c4 = (tid & 15) * 4;
#pragma unroll
      for (int p = 0; p < 8; ++p) {
        int r = p * 16 + rb;
        int gr = m0 + r;
        int gk = kt + c4;
        float4 v = make_float4(0.f, 0.f, 0.f, 0.f);
        if (gr < M) {
          const float* px = X + (size_t)gr * xpitch;
          if (gk + 3 < KK) {
            v = *(const float4*)(px + gk);
            if (aff) {
              v.x = v.x * affA[gk] + affB[gk];
              v.y = v.y * affA[gk + 1] + affB[gk + 1];
              v.z = v.z * affA[gk + 2] + affB[gk + 2];
              v.w = v.w * affA[gk + 3] + affB[gk + 3];
            }
          } else if (gk < KK) {
            float tmp[4];
#pragma unroll
            for (int j = 0; j < 4; ++j) {
              float t = 0.f;
              if (gk + j < KK) {
                t = px[gk + j];
                if (aff) t = t * affA[gk + j] + affB[gk + j];
              }
              tmp[j] = t;
            }
            v.x = tmp[0]; v.y = tmp[1]; v.z = tmp[2]; v.w = tmp[3];
          }
        }
        ushort4 o = make_ushort4(f2h(v.x), f2h(v.y), f2h(v.z), f2h(v.w));
        *(ushort4*)&Xs[r * 72 + c4] = o;
        if (xsout && gr < M) *(ushort4*)&xsout[(size_t)gr * 256 + c4] = o;  // KK==64: gk==c4
      }
    }
    // ---- stage W tile (NCT*16 cols x 64 k)
    if (wf16) {
      const unsigned short* W16 = (const unsigned short*)Wv;
#pragma unroll
      for (int p = 0; p < NCT; ++p) {
        int idx = p * 256 + tid;
        int c = idx >> 4;
        int k4 = (idx & 15) * 4;
        int gc = c0 + c, gk = kt + k4;
        uint2 val = make_uint2(0u, 0u);
        if (gc < COLS && gk + 4 <= wpitch) {
          val = *(const uint2*)(W16 + (size_t)gc * wpitch + gk);
        }
        *(uint2*)&Ws[c * 72 + k4] = val;
      }
    } else {  // fp32 W path: NCT==4 only (unused in current launches)
      const float* W = (const float*)Wv;
      int cb = tid >> 5;
      int k2 = (tid & 31) * 2;
#pragma unroll
      for (int p = 0; p < 8; ++p) {
        int c = p * 8 + cb;
        int gc = c0 + c;
        int gk = kt + k2;
        float2 v = make_float2(0.f, 0.f);
        if (gc < COLS) {
          const float* pw = W + (size_t)gc * wpitch;
          if (gk + 1 < KK) {
            v = *(const float2*)(pw + gk);
          } else if (gk < KK) {
            v.x = pw[gk];
          }
        }
        ushort2 o = make_ushort2(f2h(v.x), f2h(v.y));
        *(ushort2*)&Ws[c * 72 + k2] = o;
      }
    }
    __syncthreads();

#pragma unroll
    for (int ks = 0; ks < 64; ks += 32) {
      f16x8 a0 = *(const f16x8*)&Xs[(32 * w + l15) * 72 + ks + lhi * 8];
      f16x8 a1 = *(const f16x8*)&Xs[(32 * w + 16 + l15) * 72 + ks + lhi * 8];
#pragma unroll
      for (int ct = 0; ct < NCT; ++ct) {
        f16x8 b = *(const f16x8*)&Ws[(16 * ct + l15) * 72 + ks + lhi * 8];
        acc[0][ct] = __builtin_amdgcn_mfma_f32_16x16x32_f16(a0, b, acc[0][ct], 0, 0, 0);
        acc[1][ct] = __builtin_amdgcn_mfma_f32_16x16x32_f16(a1, b, acc[1][ct], 0, 0, 0);
      }
    }
    __syncthreads();
  }

  // ---- epilogue
  float sArr[NCT], qArr[NCT];
#pragma unroll
  for (int j = 0; j < NCT; ++j) { sArr[j] = 0.f; qArr[j] = 0.f; }
  float rdl[2][8], rdr[2][8];
#pragma unroll
  for (int h = 0; h < 2; ++h)
#pragma unroll
    for (int j = 0; j < 8; ++j) { rdl[h][j] = 0.f; rdr[h][j] = 0.f; }

#pragma unroll
  for (int rt = 0; rt < 2; ++rt) {
#pragma unroll
    for (int ct = 0; ct < NCT; ++ct) {
      int c = c0 + 16 * ct + l15;
      if (c >= COLS) continue;
      float bv = bias ? bias[c] : 0.f;
      float alc = fattn ? al[c] : 0.f;
      float arc = fattn ? ar[c] : 0.f;
#pragma unroll
      for (int reg = 0; reg < 4; ++reg) {
        int r = m0 + 32 * w + 16 * rt + lhi * 4 + reg;
        if (r >= M) continue;
        float vv = acc[rt][ct][reg] + bv;
        if (relu) vv = fmaxf(vv, 0.f);
        if (yf16)
          ((unsigned short*)Yv)[(size_t)r * ypitch + c] = f2h(vv);
        else
          ((float*)Yv)[(size_t)r * ypitch + c] = vv;
        if (fstat) { sArr[ct] += vv; qArr[ct] += vv * vv; }
        if (fattn) {
          int h = ct >> 2;  // NCT=8: cols 0-63 head0, 64-127 head1
          rdl[h][rt * 4 + reg] += vv * alc;
          rdr[h][rt * 4 + reg] += vv * arc;
        }
      }
    }
  }

  if (fattn) {
#pragma unroll
    for (int h = 0; h < 2; ++h)
#pragma unroll
      for (int j = 0; j < 8; ++j) {
        float a = rdl[h][j], b = rdr[h][j];
        a += __shfl_xor(a, 1, 64); b += __shfl_xor(b, 1, 64);
        a += __shfl_xor(a, 2, 64); b += __shfl_xor(b, 2, 64);
        a += __shfl_xor(a, 4, 64); b += __shfl_xor(b, 4, 64);
        a += __shfl_xor(a, 8, 64); b += __shfl_xor(b, 8, 64);
        rdl[h][j] = a; rdr[h][j] = b;
      }
    if (l15 == 0) {
#pragma unroll
      for (int j = 0; j < 8; ++j) {
        int r = m0 + 32 * w + 16 * (j >> 2) + lhi * 4 + (j & 3);
        if (r < M) {
          el[(size_t)r * 2 + 0] = rdl[0][j];
          el[(size_t)r * 2 + 1] = rdl[1][j];
          er[(size_t)r * 2 + 0] = rdr[0][j];
          er[(size_t)r * 2 + 1] = rdr[1][j];
        }
      }
    }
  }

  if (fstat) {  // NCT==4 path
#pragma unroll
    for (int ct = 0; ct < NCT; ++ct) {
      float s = sArr[ct], q = qArr[ct];
      s += __shfl_xor(s, 16, 64); q += __shfl_xor(q, 16, 64);
      s += __shfl_xor(s, 32, 64); q += __shfl_xor(q, 32, 64);
      if (lhi == 0) {
        affA[w * 64 + ct * 16 + l15] = s;
        affB[w * 64 + ct * 16 + l15] = q;
      }
    }
    __syncthreads();
    if (tid < 64) {
      float s = affA[tid] + affA[64 + tid] + affA[128 + tid] + affA[192 + tid];
      float q = affB[tid] + affB[64 + tid] + affB[128 + tid] + affB[192 + tid];
      atomicAdd(&ostats[tid], s);
      atomicAdd(&ostats[64 + tid], q);
    }
  }
}

// ---------------------------------------------------------------------------
// GAT aggregation (half-wave pairing, 8-pair unroll; at its random-line
// gather floor ~3.5 TB/s — r10/r11 measured). Output fp16 (g16).
// ---------------------------------------------------------------------------
__global__ __launch_bounds__(256) void k_agg(const int* __restrict__ rowptr,
                                             const unsigned short* __restrict__ csr16,
                                             const unsigned short* __restrict__ feat16,
                                             const float* __restrict__ el,
                                             const float* __restrict__ er, const float* __restrict__ gatb,
                                             unsigned short* __restrict__ g16, int n) {
  int v = blockIdx.x * 4 + (threadIdx.x >> 6);
  if (v >= n) return;
  int lane = threadIdx.x & 63;
  int grp = lane >> 5;
  int sub = lane & 31;
  int head = sub >> 4;
  int beg = rowptr[v], end = rowptr[v + 1];
  float er0 = er[(size_t)v * 2 + 0], er1 = er[(size_t)v * 2 + 1];
  float s0 = 0.f, s1 = 0.f;
  float a0 = 0.f, a1 = 0.f, a2 = 0.f, a3 = 0.f;
  const char* fb = (const char*)feat16;
  int sub8 = sub * 8;
  for (int base = beg; base < end; base += 64) {
    int nch = min(64, end - base);
    int uoff_l = 0;
    float w0_l = 0.f, w1_l = 0.f;
    if (base + lane < end) {
      int u = csr16[base + lane];
      uoff_l = u * 256;
      float2 tt = *(const float2*)&el[(size_t)u * 2];
      float e0 = tt.x + er0, e1 = tt.y + er1;
      e0 = (e0 > 0.f) ? e0 : 0.2f * e0;
      e1 = (e1 > 0.f) ? e1 : 0.2f * e1;
      w0_l = __expf(e0);
      w1_l = __expf(e1);
      s0 += w0_l;
      s1 += w1_l;
    }
    int i = 0;
    for (; i + 16 <= nch; i += 16) {
      uint2 q[8];
#pragma unroll
      for (int p = 0; p < 8; ++p) {
        int e = i + 2 * p + grp;
        int uo = __shfl(uoff_l, e);
        q[p] = *(const uint2*)(fb + (size_t)(unsigned)uo + sub8);
      }
#pragma unroll
      for (int p = 0; p < 8; ++p) {
        int e = i + 2 * p + grp;
        float wa = __shfl(w0_l, e);
        float wb = __shfl(w1_l, e);
        float wgt = head ? wb : wa;
        float2 fx = h2f2(q[p].x);
        float2 fy = h2f2(q[p].y);
        a0 += wgt * fx.x;
        a1 += wgt * fx.y;
        a2 += wgt * fy.x;
        a3 += wgt * fy.y;
      }
    }
    for (; i + 8 <= nch; i += 8) {
      uint2 q[4];
#pragma unroll
      for (int p = 0; p < 4; ++p) {
        int e = i + 2 * p + grp;
        int uo = __shfl(uoff_l, e);
        q[p] = *(const uint2*)(fb + (size_t)(unsigned)uo + sub8);
      }
#pragma unroll
      for (int p = 0; p < 4; ++p) {
        int e = i + 2 * p + grp;
        float wa = __shfl(w0_l, e);
        float wb = __shfl(w1_l, e);
        float wgt = head ? wb : wa;
        float2 fx = h2f2(q[p].x);
        float2 fy = h2f2(q[p].y);
        a0 += wgt * fx.x;
        a1 += wgt * fx.y;
        a2 += wgt * fy.x;
        a3 += wgt * fy.y;
      }
    }
    for (; i < nch; i += 2) {
      int e = i + grp;
      int ec = min(e, nch - 1);
      int uo = __shfl(uoff_l, ec);
      float wa = __shfl(w0_l, ec);
      float wb = __shfl(w1_l, ec);
      float wgt = head ? wb : wa;
      if (e >= nch) wgt = 0.f;
      uint2 q = *(const uint2*)(fb + (size_t)(unsigned)uo + sub8);
      float2 fx = h2f2(q.x);
      float2 fy = h2f2(q.y);
      a0 += wgt * fx.x;
      a1 += wgt * fx.y;
      a2 += wgt * fy.x;
      a3 += wgt * fy.y;
    }
  }
  a0 += __shfl_xor(a0, 32, 64);
  a1 += __shfl_xor(a1, 32, 64);
  a2 += __shfl_xor(a2, 32, 64);
  a3 += __shfl_xor(a3, 32, 64);
  for (int o = 32; o > 0; o >>= 1) {
    s0 += __shfl_xor(s0, o, 64);
    s1 += __shfl_xor(s1, o, 64);
  }
  if (lane < 32) {
    float s = head ? s1 : s0;
    float inv = (end > beg) ? 1.f / s : 0.f;
    int c = 4 * sub;
    ushort4 o4;
    o4.x = f2h(a0 * inv + gatb[c]);
    o4.y = f2h(a1 * inv + gatb[c + 1]);
    o4.z = f2h(a2 * inv + gatb[c + 2]);
    o4.w = f2h(a3 * inv + gatb[c + 3]);
    *(ushort4*)&g16[(size_t)v * 128 + c] = o4;
  }
}

// ---------------------------------------------------------------------------
// column stats (sum, sumsq) over an fp16 matrix. C divides 256.
// ---------------------------------------------------------------------------
__global__ __launch_bounds__(256) void k_colstats16(const unsigned short* __restrict__ Z, int pitch,
                                                    int C, int M, float* __restrict__ stats) {
  __shared__ float ls[256];
  __shared__ float lq[256];
  int t = threadIdx.x;
  int c = t % C;
  int rpb = 256 / C;
  int r = blockIdx.x * rpb + t / C;
  int stride = gridDim.x * rpb;
  float s = 0.f, q = 0.f;
  const _Float16* Zh = (const _Float16*)Z;
  for (; r < M; r += stride) {
    float v = (float)Zh[(size_t)r * pitch + c];
    s += v;
    q += v * v;
  }
  ls[t] = s;
  lq[t] = q;
  __syncthreads();
  if (t < C) {
    for (int i = 1; i < rpb; ++i) {
      s += ls[t + i * C];
      q += lq[t + i * C];
    }
    atomicAdd(&stats[c], s);
    atomicAdd(&stats[C + c], q);
  }
}

// bn2 apply (last layer only — earlier layers fused into next fc's staging)
__global__ __launch_bounds__(256) void k_bnapply(const float* __restrict__ u, const float* __restrict__ stats,
                                                 const float* __restrict__ gam, const float* __restrict__ bet,
                                                 unsigned short* __restrict__ yout, int n, float invM) {
  int idx = blockIdx.x * 256 + threadIdx.x;
  if (idx >= n * 16) return;
  int r = idx >> 4, c4 = (idx & 15) * 4;
  float4 uu = *(const float4*)&u[(size_t)r * 64 + c4];
  float vv[4] = {uu.x, uu.y, uu.z, uu.w};
  ushort4 o;
  unsigned short* op = (unsigned short*)&o;
#pragma unroll
  for (int j = 0; j < 4; ++j) {
    int c = c4 + j;
    float mean = stats[c] * invM;
    float var = stats[64 + c] * invM - mean * mean;
    float a = gam[c] * rsqrtf(var + BN_EPS);
    float b = bet[c] - mean * a;
    op[j] = f2h(a * vv[j] + b);
  }
  *(ushort4*)&yout[(size_t)r * 256 + c4] = o;
}

// final: out[n] = sum_j relu(bn(y[n,j])) * w2[j]. One wave per row.
__global__ __launch_bounds__(256) void k_final(const float* __restrict__ y, const float* __restrict__ stats,
                                               const float* __restrict__ gam, const float* __restrict__ bet,
                                               const float* __restrict__ w2, float* __restrict__ out, int n,
                                               float invM) {
  int v = blockIdx.x * 4 + (threadIdx.x >> 6);
  if (v >= n) return;
  int lane = threadIdx.x & 63;
  float mean = stats[lane] * invM;
  float var = stats[64 + lane] * invM - mean * mean;
  float a = gam[lane] * rsqrtf(var + BN_EPS);
  float b = bet[lane] - mean * a;
  float h = a * y[(size_t)v * 64 + lane] + b;
  h = fmaxf(h, 0.f) * w2[lane];
  for (int o = 32; o > 0; o >>= 1) h += __shfl_down(h, o, 64);
  if (lane == 0) out[v] = h;
}

// ---------------------------------------------------------------------------
extern "C" void kernel_launch(void* const* d_in, const int* in_sizes, int n_in,
                              void* d_out, int out_size, void* d_ws, size_t ws_size,
                              hipStream_t stream) {
  const float* x = (const float*)d_in[0];
  const int* src = (const int*)d_in[1];
  const int* dst = (const int*)d_in[2];
  const float* emb_w = (const float*)d_in[3];
  const float* emb_b = (const float*)d_in[4];
  const float* fc_w = (const float*)d_in[5];
  const float* attn_l = (const float*)d_in[6];
  const float* attn_r = (const float*)d_in[7];
  const float* gat_b = (const float*)d_in[8];
  const float* bn1_g = (const float*)d_in[9];
  const float* bn1_b = (const float*)d_in[10];
  const float* ff_w1 = (const float*)d_in[11];
  const float* ff_b1 = (const float*)d_in[12];
  const float* ff_w2 = (const float*)d_in[13];
  const float* ff_b2 = (const float*)d_in[14];
  const float* bn2_g = (const float*)d_in[15];
  const float* bn2_b = (const float*)d_in[16];
  const float* mlp_w1 = (const float*)d_in[17];
  const float* mlp_bn_g = (const float*)d_in[18];
  const float* mlp_bn_b = (const float*)d_in[19];
  const float* mlp_w2 = (const float*)d_in[20];
  float* out = (float*)d_out;
  (void)n_in;
  (void)out_size;

  const int n = in_sizes[0] / 64;  // 50000
  const int E = in_sizes[1];       // 1600000
  const int NL = 3;
  const int nbuk = (n + 127) >> 7;

  char* wsb = (char*)d_ws;
  size_t off = 0;
  auto alloc = [&](size_t bytes) {
    size_t o = off;
    off = (off + bytes + 255) & ~(size_t)255;
    return o;
  };
  size_t o_bcnt = alloc((size_t)512 * 4);
  size_t o_stats = alloc(1280 * 4);
  size_t zero_bytes = off;
  size_t o_rowptr = alloc((size_t)(n + 1) * 4);
  size_t o_bcur = alloc((size_t)512 * 4);
  size_t o_bbase = alloc((size_t)512 * 4);
  size_t o_csr = alloc((size_t)E * 2);
  size_t o_pairs = alloc((size_t)E * 4);
  size_t o_feat = alloc((size_t)n * 128 * 2);      // feat16 fp16
  size_t o_u = alloc((size_t)n * 64 * 4);          // u fp32 (separate: fc reads u while writing feat16)
  size_t o_g = alloc((size_t)n * 128 * 2);         // g16 fp16
  size_t o_t = alloc((size_t)n * 224 * 2 + 256);   // t16, pitch 224 halves
  size_t o_xs = alloc((size_t)n * 256 * 2);        // xs16 concat [n,256] fp16
  size_t o_el = alloc((size_t)n * 2 * 4);
  size_t o_er = alloc((size_t)n * 2 * 4);
  const int n_emb = 64 * 64;
  const int n_fc = NL * 128 * 64;
  const int n_w2rows = NL * 64;
  const int n_mlp = 64 * 256;
  size_t o_embw = alloc((size_t)n_emb * 2);
  size_t o_fcw = alloc((size_t)n_fc * 2);
  size_t o_w2w = alloc((size_t)n_w2rows * 224 * 2);
  size_t o_mlpw = alloc((size_t)n_mlp * 2);
  size_t o_w1f = alloc((size_t)218 * 128 * 2);
  size_t o_b1p = alloc((size_t)224 * 4);
  if (off > ws_size) return;

  int* bcnt = (int*)(wsb + o_bcnt);
  float* stats = (float*)(wsb + o_stats);
  int* rowptr = (int*)(wsb + o_rowptr);
  int* bcur = (int*)(wsb + o_bcur);
  int* bbase = (int*)(wsb + o_bbase);
  unsigned short* csr16 = (unsigned short*)(wsb + o_csr);
  unsigned int* pairs = (unsigned int*)(wsb + o_pairs);
  unsigned short* feat16 = (unsigned short*)(wsb + o_feat);
  float* u = (float*)(wsb + o_u);
  unsigned short* g16 = (unsigned short*)(wsb + o_g);
  unsigned short* t16 = (unsigned short*)(wsb + o_t);
  unsigned short* xs16 = (unsigned short*)(wsb + o_xs);
  float* el = (float*)(wsb + o_el);
  float* er = (float*)(wsb + o_er);
  unsigned short* embw16 = (unsigned short*)(wsb + o_embw);
  unsigned short* fcw16 = (unsigned short*)(wsb + o_fcw);
  unsigned short* w2w16 = (unsigned short*)(wsb + o_w2w);
  unsigned short* mlpw16 = (unsigned short*)(wsb + o_mlpw);
  unsigned short* w1f16 = (unsigned short*)(wsb + o_w1f);
  float* b1p = (float*)(wsb + o_b1p);

  hipMemsetAsync(d_ws, 0, zero_bytes, stream);

  int gchunk = (E + CHUNK - 1) / CHUNK;
  k_bcount<<<gchunk, 256, 0, stream>>>(dst, bcnt, E);
  k_bscan<<<1, 512, 0, stream>>>(bcnt, bcur, bbase, nbuk);
  k_bucket<<<gchunk, 256, 0, stream>>>(src, dst, bcur, pairs, E);
  k_place<<<nbuk, 256, 0, stream>>>(bbase, pairs, csr16, rowptr, n, nbuk, E);

  int cvt_total = n_emb + n_fc + n_w2rows * 224 + n_mlp;
  k_cvtw<<<(cvt_total + 255) / 256, 256, 0, stream>>>(emb_w, fc_w, ff_w2, mlp_w1,
                                                      embw16, fcw16, w2w16, mlpw16,
                                                      n_emb, n_fc, n_w2rows, n_mlp);

  int gm = (n + 127) / 128;
  float invM = 1.f / (float)n;

  // embedding -> xs16[:, 0:64)   (X fp32, W fp16, Y fp16)
  k_gemm<4><<<dim3(gm, 1), 256, 0, stream>>>(x, 64, embw16, 64, emb_b, nullptr, nullptr, nullptr, invM,
                                             xs16, 256, n, 64, 64, 4 | 64,
                                             nullptr, nullptr, nullptr, nullptr, nullptr, nullptr);

  for (int l = 0; l < NL; ++l) {
    float* sbn1 = stats + l * 384;
    float* sbn2 = stats + l * 384 + 256;
    // fc: feat16 = h @ fc_w^T + fused attn logits, 128 cols/block.
    // l==0: X = xs16 slice0 (fp16). l>0: X = u + bn2 affine (fused bnapply),
    // side-writing the affined fp16 tile into xs16 slice l.
    if (l == 0) {
      k_gemm<8><<<dim3(gm, 1), 256, 0, stream>>>(xs16, 256, fcw16, 64,
                                                 nullptr, nullptr, nullptr, nullptr, invM,
                                                 feat16, 128, n, 64, 128, 4 | 8 | 32 | 64,
                                                 nullptr, attn_l, attn_r, el, er, nullptr);
    } else {
      float* sprev = stats + (l - 1) * 384 + 256;
      k_gemm<8><<<dim3(gm, 1), 256, 0, stream>>>(u, 64, fcw16 + (size_t)l * 128 * 64, 64,
                                                 nullptr, sprev, bn2_g + (l - 1) * 64, bn2_b + (l - 1) * 64,
                                                 invM, feat16, 128, n, 64, 128, 2 | 4 | 32 | 64,
                                                 nullptr, attn_l + l * 128, attn_r + l * 128, el, er,
                                                 xs16 + 64 * l);
    }
    k_agg<<<(n + 3) / 4, 256, 0, stream>>>(rowptr, csr16, feat16, el, er, gat_b + l * 128, g16, n);
    k_colstats16<<<512, 256, 0, stream>>>(g16, 128, 128, n, sbn1);
    k_foldw1<<<(218 + 3) / 4, 256, 0, stream>>>(ff_w1 + (size_t)l * 218 * 128, ff_b1 + l * 218,
                                                sbn1, bn1_g + l * 128, bn1_b + l * 128, invM,
                                                w1f16, b1p, 218, 128);
    // ff1: t16 = relu(g16 @ W1'^T + b1'), 128 cols/block (grid.y=2)
    k_gemm<8><<<dim3(gm, 2), 256, 0, stream>>>(g16, 128, w1f16, 128, b1p,
                                               nullptr, nullptr, nullptr, invM,
                                               t16, 224, n, 128, 218, 1 | 4 | 8 | 64,
                                               nullptr, nullptr, nullptr, nullptr, nullptr, nullptr);
    // ff2: u = t16 @ W2^T + b2   (fused bn2 col-stats)
    k_gemm<4><<<dim3(gm, 1), 256, 0, stream>>>(t16, 224, w2w16 + (size_t)l * 64 * 224, 224, ff_b2 + l * 64,
                                               nullptr, nullptr, nullptr, invM,
                                               u, 64, n, 218, 64, 8 | 16 | 64,
                                               sbn2, nullptr, nullptr, nullptr, nullptr, nullptr);
    if (l == NL - 1) {
      k_bnapply<<<(n * 16 + 255) / 256, 256, 0, stream>>>(u, sbn2, bn2_g + l * 64, bn2_b + l * 64,
                                                          xs16 + 64 * (l + 1), n, invM);
    }
  }

  float* smlp = stats + 1152;
  // mlp: u = xs16 @ mlp_w1^T   (fused col-stats)
  k_gemm<4><<<dim3(gm, 1), 256, 0, stream>>>(xs16, 256, mlpw16, 256, nullptr, nullptr, nullptr, nullptr,
                                             invM, u, 64, n, 256, 64, 8 | 16 | 64,
                                             smlp, nullptr, nullptr, nullptr, nullptr, nullptr);
  k_final<<<(n + 3) / 4, 256, 0, stream>>>(u, smlp, mlp_bn_g, mlp_bn_b, mlp_w2, out, n, invM);
}

// Round 14
// 703.882 us; speedup vs baseline: 1.0173x; 1.0173x over previous
//
#include <hip/hip_runtime.h>
#include <cstdint>

#define BN_EPS 1e-5f

typedef _Float16 f16x8 __attribute__((ext_vector_type(8)));
typedef _Float16 f16x2 __attribute__((ext_vector_type(2)));
typedef float f32x4 __attribute__((ext_vector_type(4)));

__device__ __forceinline__ unsigned short f2h(float f) {
  _Float16 h = (_Float16)f;
  return *(unsigned short*)&h;
}
__device__ __forceinline__ float2 h2f2(unsigned int q) {
  f16x2 h = __builtin_bit_cast(f16x2, q);
  return make_float2((float)h.x, (float)h.y);
}

// ---------------------------------------------------------------------------
// CSR build (by dst), once per call — bucket-first, no per-node atomics.
// ---------------------------------------------------------------------------
#define CHUNK 8192
#define MAXBUK 512

__global__ __launch_bounds__(256) void k_bcount(const int* __restrict__ dst, int* __restrict__ bcnt, int E) {
  __shared__ int hist[MAXBUK];
  int tid = threadIdx.x;
  int base = blockIdx.x * CHUNK;
  int cnt = min(CHUNK, E - base);
  if (cnt <= 0) return;
  for (int b = tid; b < MAXBUK; b += 256) hist[b] = 0;
  __syncthreads();
  for (int i = tid; i < cnt; i += 256) atomicAdd(&hist[dst[base + i] >> 7], 1);
  __syncthreads();
  for (int b = tid; b < MAXBUK; b += 256) {
    int c = hist[b];
    if (c > 0) atomicAdd(&bcnt[b], c);
  }
}

__global__ __launch_bounds__(512) void k_bscan(const int* __restrict__ bcnt, int* __restrict__ bcur,
                                               int* __restrict__ bbase, int nbuk) {
  __shared__ int sh[512];
  int t = threadIdx.x;
  int v = (t < nbuk) ? bcnt[t] : 0;
  sh[t] = v;
  __syncthreads();
  for (int off = 1; off < 512; off <<= 1) {
    int u = (t >= off) ? sh[t - off] : 0;
    __syncthreads();
    sh[t] += u;
    __syncthreads();
  }
  if (t < nbuk) {
    int excl = sh[t] - v;
    bcur[t] = excl;
    bbase[t] = excl;
  }
}

__global__ __launch_bounds__(256) void k_bucket(const int* __restrict__ src, const int* __restrict__ dst,
                                                int* __restrict__ bcur, unsigned int* __restrict__ pairs,
                                                int E) {
  __shared__ unsigned int ep[CHUNK];
  __shared__ int bcnt[MAXBUK];
  __shared__ int gbase[MAXBUK];
  __shared__ int rcnt[MAXBUK];
  int tid = threadIdx.x;
  int base = blockIdx.x * CHUNK;
  int cnt = min(CHUNK, E - base);
  if (cnt <= 0) return;

  for (int b = tid; b < MAXBUK; b += 256) { bcnt[b] = 0; rcnt[b] = 0; }
  __syncthreads();
  for (int i = tid; i < cnt; i += 256) {
    int d = dst[base + i];
    int s = src[base + i];
    unsigned int pk = ((unsigned)(d >> 7) << 23) | ((unsigned)(d & 127) << 16) | (unsigned)s;
    ep[i] = pk;
    atomicAdd(&bcnt[d >> 7], 1);
  }
  __syncthreads();
  for (int b = tid; b < MAXBUK; b += 256) {
    int c = bcnt[b];
    gbase[b] = (c > 0) ? atomicAdd(&bcur[b], c) : 0;
  }
  __syncthreads();
  for (int i = tid; i < cnt; i += 256) {
    unsigned int pk = ep[i];
    int bk = pk >> 23;
    int r = atomicAdd(&rcnt[bk], 1);
    pairs[gbase[bk] + r] = pk & 0x007FFFFFu;
  }
}

#define PLACE_CAP 24576

__global__ __launch_bounds__(256) void k_place(const int* __restrict__ bbase,
                                               const unsigned int* __restrict__ pairs,
                                               unsigned short* __restrict__ csr16,
                                               int* __restrict__ rowptr, int n, int nbuk, int E) {
  __shared__ unsigned short stage[PLACE_CAP];
  __shared__ int nc[128];
  __shared__ int nstart[128];
  __shared__ int nrun[128];
  int tid = threadIdx.x;
  int bk = blockIdx.x;
  int v0 = bk * 128;
  int beg = bbase[bk];
  int end = (bk + 1 < nbuk) ? bbase[bk + 1] : E;
  int cnt = end - beg;
  if (tid < 128) { nc[tid] = 0; nrun[tid] = 0; }
  __syncthreads();
  for (int i = tid; i < cnt; i += 256) atomicAdd(&nc[(pairs[beg + i] >> 16) & 127], 1);
  __syncthreads();
  if (tid < 128) nstart[tid] = nc[tid];
  __syncthreads();
  for (int off = 1; off < 128; off <<= 1) {
    int v = (tid < 128 && tid >= off) ? nstart[tid - off] : 0;
    __syncthreads();
    if (tid < 128) nstart[tid] += v;
    __syncthreads();
  }
  if (tid < 128) nstart[tid] -= nc[tid];
  __syncthreads();
  if (tid < 128 && v0 + tid < n) rowptr[v0 + tid] = beg + nstart[tid];
  if (bk == nbuk - 1 && tid == 0) rowptr[n] = E;
  if (cnt <= 0) return;
  if (cnt <= PLACE_CAP) {
    for (int i = tid; i < cnt; i += 256) {
      unsigned int p = pairs[beg + i];
      int dlow = (p >> 16) & 127;
      int r = atomicAdd(&nrun[dlow], 1);
      stage[nstart[dlow] + r] = (unsigned short)(p & 0xFFFF);
    }
    __syncthreads();
    for (int i = tid; i < cnt; i += 256) csr16[beg + i] = stage[i];
  } else {
    for (int i = tid; i < cnt; i += 256) {
      unsigned int p = pairs[beg + i];
      int dlow = (p >> 16) & 127;
      int r = atomicAdd(&nrun[dlow], 1);
      csr16[beg + nstart[dlow] + r] = (unsigned short)(p & 0xFFFF);
    }
  }
}

// ---------------------------------------------------------------------------
// one-shot fp32 -> fp16 conversion of all static weights (per call).
// ff_w2 rows padded 218 -> 224 halves (zero fill).
// ---------------------------------------------------------------------------
__global__ __launch_bounds__(256) void k_cvtw(
    const float* __restrict__ emb, const float* __restrict__ fc,
    const float* __restrict__ w2, const float* __restrict__ mlp,
    unsigned short* __restrict__ o_emb, unsigned short* __restrict__ o_fc,
    unsigned short* __restrict__ o_w2, unsigned short* __restrict__ o_mlp,
    int n_emb, int n_fc, int n_w2rows, int n_mlp) {
  int idx = blockIdx.x * 256 + threadIdx.x;
  if (idx < n_emb) { o_emb[idx] = f2h(emb[idx]); return; }
  idx -= n_emb;
  if (idx < n_fc) { o_fc[idx] = f2h(fc[idx]); return; }
  idx -= n_fc;
  int w2tot = n_w2rows * 224;
  if (idx < w2tot) {
    int r = idx / 224, c = idx - r * 224;
    o_w2[idx] = f2h((c < 218) ? w2[r * 218 + c] : 0.f);
    return;
  }
  idx -= w2tot;
  if (idx < n_mlp) o_mlp[idx] = f2h(mlp[idx]);
}

// ---------------------------------------------------------------------------
// fold bn1 affine into ff1 weights (per layer, after bn1 stats).
// ---------------------------------------------------------------------------
__global__ __launch_bounds__(256) void k_foldw1(const float* __restrict__ W1, const float* __restrict__ b1,
                                                const float* __restrict__ stats, const float* __restrict__ gam,
                                                const float* __restrict__ bet, float invM,
                                                unsigned short* __restrict__ W16, float* __restrict__ b1p,
                                                int rows, int K) {
  __shared__ float aA[128];
  __shared__ float aB[128];
  int tid = threadIdx.x;
  if (tid < K) {
    float mean = stats[tid] * invM;
    float var = stats[K + tid] * invM - mean * mean;
    float a = gam[tid] * rsqrtf(var + BN_EPS);
    aA[tid] = a;
    aB[tid] = bet[tid] - mean * a;
  }
  __syncthreads();
  int w = tid >> 6, lane = tid & 63;
  int i = blockIdx.x * 4 + w;
  if (i >= rows) return;
  const float* wr = W1 + (size_t)i * K;
  float dot = 0.f;
  for (int k = lane; k < K; k += 64) {
    float wv = wr[k];
    W16[(size_t)i * K + k] = f2h(wv * aA[k]);
    dot += wv * aB[k];
  }
  for (int o = 32; o > 0; o >>= 1) dot += __shfl_down(dot, o, 64);
  if (lane == 0) b1p[i] = b1[i] + dot;
}

// ---------------------------------------------------------------------------
// fp16-MFMA GEMM (r12 shape: 128 rows x 64 cols, 256 threads = 4 waves).
// flags: bit0 relu | bit1 input BN affine (fp32 X only) | bit2 Y fp16 |
//        bit3 X fp16 | bit4 fused col-stats (COLS<=64, grid.y=1) |
//        bit5 fused attn logits (COLS=128, head=blockIdx.y) | bit6 W fp16
// xsout != nullptr (KK==64, fp32-X path): blockIdx.y==0 side-writes the
// affined fp16 X tile to xsout (pitch 256) — fuses prev layer's bn2-apply.
// ---------------------------------------------------------------------------
__global__ __launch_bounds__(256) void k_gemm(
    const void* __restrict__ Xv, int xpitch,
    const void* __restrict__ Wv, int wpitch,
    const float* __restrict__ bias,
    const float* __restrict__ stats, const float* __restrict__ gamma, const float* __restrict__ beta,
    float invM, void* __restrict__ Yv, int ypitch,
    int M, int KK, int COLS, int flags,
    float* __restrict__ ostats,
    const float* __restrict__ al, const float* __restrict__ ar,
    float* __restrict__ el, float* __restrict__ er,
    unsigned short* __restrict__ xsout) {
  __shared__ unsigned short Xs[128 * 72];
  __shared__ unsigned short Ws[64 * 72];
  __shared__ float affA[256];
  __shared__ float affB[256];

  int tid = threadIdx.x;
  int m0 = blockIdx.x * 128;
  int c0 = blockIdx.y * 64;
  const bool relu = (flags & 1) != 0;
  const bool aff = (flags & 2) != 0;
  const bool yf16 = (flags & 4) != 0;
  const bool xf16 = (flags & 8) != 0;
  const bool fstat = (flags & 16) != 0;
  const bool fattn = (flags & 32) != 0;
  const bool wf16 = (flags & 64) != 0;

  if (aff) {
    if (tid < KK && tid < 256) {
      float mean = stats[tid] * invM;
      float var = stats[KK + tid] * invM - mean * mean;
      float a = gamma[tid] * rsqrtf(var + BN_EPS);
      affA[tid] = a;
      affB[tid] = beta[tid] - mean * a;
    }
    __syncthreads();
  }

  int w = tid >> 6;
  int lane = tid & 63;
  int l15 = lane & 15;
  int lhi = lane >> 4;

  f32x4 acc[2][4];
#pragma unroll
  for (int i = 0; i < 2; ++i)
#pragma unroll
    for (int j = 0; j < 4; ++j) acc[i][j] = (f32x4){0.f, 0.f, 0.f, 0.f};

  for (int kt = 0; kt < KK; kt += 64) {
    // ---- stage X tile (128 x 64 halves)
    if (xf16) {
      const unsigned short* X16 = (const unsigned short*)Xv;
#pragma unroll
      for (int p = 0; p < 4; ++p) {
        int idx = p * 256 + tid;
        int r = idx >> 3;
        int k8 = (idx & 7) * 8;
        int gr = m0 + r, gk = kt + k8;
        if (gr < M && gk + 8 <= KK) {
          *(uint4*)&Xs[r * 72 + k8] = *(const uint4*)(X16 + (size_t)gr * xpitch + gk);
        } else {
#pragma unroll
          for (int j = 0; j < 8; ++j)
            Xs[r * 72 + k8 + j] =
                (gr < M && gk + j < KK) ? X16[(size_t)gr * xpitch + gk + j] : (unsigned short)0;
        }
      }
    } else {
      const float* X = (const float*)Xv;
      int rb = tid >> 4;
      int c4 = (tid & 15) * 4;
#pragma unroll
      for (int p = 0; p < 8; ++p) {
        int r = p * 16 + rb;
        int gr = m0 + r;
        int gk = kt + c4;
        float4 v = make_float4(0.f, 0.f, 0.f, 0.f);
        if (gr < M) {
          const float* px = X + (size_t)gr * xpitch;
          if (gk + 3 < KK) {
            v = *(const float4*)(px + gk);
            if (aff) {
              v.x = v.x * affA[gk] + affB[gk];
              v.y = v.y * affA[gk + 1] + affB[gk + 1];
              v.z = v.z * affA[gk + 2] + affB[gk + 2];
              v.w = v.w * affA[gk + 3] + affB[gk + 3];
            }
          } else if (gk < KK) {
            float tmp[4];
#pragma unroll
            for (int j = 0; j < 4; ++j) {
              float t = 0.f;
              if (gk + j < KK) {
                t = px[gk + j];
                if (aff) t = t * affA[gk + j] + affB[gk + j];
              }
              tmp[j] = t;
            }
            v.x = tmp[0]; v.y = tmp[1]; v.z = tmp[2]; v.w = tmp[3];
          }
        }
        ushort4 o = make_ushort4(f2h(v.x), f2h(v.y), f2h(v.z), f2h(v.w));
        *(ushort4*)&Xs[r * 72 + c4] = o;
        if (xsout && blockIdx.y == 0 && gr < M)
          *(ushort4*)&xsout[(size_t)gr * 256 + c4] = o;  // KK==64: gk==c4
      }
    }
    // ---- stage W tile (64 cols x 64 k)
    if (wf16) {
      const unsigned short* W16 = (const unsigned short*)Wv;
#pragma unroll
      for (int p = 0; p < 4; ++p) {
        int idx = p * 256 + tid;
        int c = idx >> 4;
        int k4 = (idx & 15) * 4;
        int gc = c0 + c, gk = kt + k4;
        uint2 val = make_uint2(0u, 0u);
        if (gc < COLS && gk + 4 <= wpitch) {
          val = *(const uint2*)(W16 + (size_t)gc * wpitch + gk);
        }
        *(uint2*)&Ws[c * 72 + k4] = val;
      }
    } else {
      const float* W = (const float*)Wv;
      int cb = tid >> 5;
      int k2 = (tid & 31) * 2;
#pragma unroll
      for (int p = 0; p < 8; ++p) {
        int c = p * 8 + cb;
        int gc = c0 + c;
        int gk = kt + k2;
        float2 v = make_float2(0.f, 0.f);
        if (gc < COLS) {
          const float* pw = W + (size_t)gc * wpitch;
          if (gk + 1 < KK) {
            v = *(const float2*)(pw + gk);
          } else if (gk < KK) {
            v.x = pw[gk];
          }
        }
        ushort2 o = make_ushort2(f2h(v.x), f2h(v.y));
        *(ushort2*)&Ws[c * 72 + k2] = o;
      }
    }
    __syncthreads();

#pragma unroll
    for (int ks = 0; ks < 64; ks += 32) {
      f16x8 a0 = *(const f16x8*)&Xs[(32 * w + l15) * 72 + ks + lhi * 8];
      f16x8 a1 = *(const f16x8*)&Xs[(32 * w + 16 + l15) * 72 + ks + lhi * 8];
#pragma unroll
      for (int ct = 0; ct < 4; ++ct) {
        f16x8 b = *(const f16x8*)&Ws[(16 * ct + l15) * 72 + ks + lhi * 8];
        acc[0][ct] = __builtin_amdgcn_mfma_f32_16x16x32_f16(a0, b, acc[0][ct], 0, 0, 0);
        acc[1][ct] = __builtin_amdgcn_mfma_f32_16x16x32_f16(a1, b, acc[1][ct], 0, 0, 0);
      }
    }
    __syncthreads();
  }

  // ---- epilogue
  float sArr[4] = {0.f, 0.f, 0.f, 0.f}, qArr[4] = {0.f, 0.f, 0.f, 0.f};
  float rdl[8], rdr[8];
#pragma unroll
  for (int j = 0; j < 8; ++j) { rdl[j] = 0.f; rdr[j] = 0.f; }

#pragma unroll
  for (int rt = 0; rt < 2; ++rt) {
#pragma unroll
    for (int ct = 0; ct < 4; ++ct) {
      int c = c0 + 16 * ct + l15;
      if (c >= COLS) continue;
      float bv = bias ? bias[c] : 0.f;
      float alc = fattn ? al[c] : 0.f;
      float arc = fattn ? ar[c] : 0.f;
#pragma unroll
      for (int reg = 0; reg < 4; ++reg) {
        int r = m0 + 32 * w + 16 * rt + lhi * 4 + reg;
        if (r >= M) continue;
        float vv = acc[rt][ct][reg] + bv;
        if (relu) vv = fmaxf(vv, 0.f);
        if (yf16)
          ((unsigned short*)Yv)[(size_t)r * ypitch + c] = f2h(vv);
        else
          ((float*)Yv)[(size_t)r * ypitch + c] = vv;
        if (fstat) { sArr[ct] += vv; qArr[ct] += vv * vv; }
        if (fattn) { rdl[rt * 4 + reg] += vv * alc; rdr[rt * 4 + reg] += vv * arc; }
      }
    }
  }

  if (fattn) {
#pragma unroll
    for (int j = 0; j < 8; ++j) {
      float a = rdl[j], b = rdr[j];
      a += __shfl_xor(a, 1, 64); b += __shfl_xor(b, 1, 64);
      a += __shfl_xor(a, 2, 64); b += __shfl_xor(b, 2, 64);
      a += __shfl_xor(a, 4, 64); b += __shfl_xor(b, 4, 64);
      a += __shfl_xor(a, 8, 64); b += __shfl_xor(b, 8, 64);
      rdl[j] = a; rdr[j] = b;
    }
    if (l15 == 0) {
      int hy = blockIdx.y;
#pragma unroll
      for (int j = 0; j < 8; ++j) {
        int r = m0 + 32 * w + 16 * (j >> 2) + lhi * 4 + (j & 3);
        if (r < M) {
          el[(size_t)r * 2 + hy] = rdl[j];
          er[(size_t)r * 2 + hy] = rdr[j];
        }
      }
    }
  }

  if (fstat) {
#pragma unroll
    for (int ct = 0; ct < 4; ++ct) {
      float s = sArr[ct], q = qArr[ct];
      s += __shfl_xor(s, 16, 64); q += __shfl_xor(q, 16, 64);
      s += __shfl_xor(s, 32, 64); q += __shfl_xor(q, 32, 64);
      if (lhi == 0) {
        affA[w * 64 + ct * 16 + l15] = s;
        affB[w * 64 + ct * 16 + l15] = q;
      }
    }
    __syncthreads();
    if (tid < 64) {
      float s = affA[tid] + affA[64 + tid] + affA[128 + tid] + affA[192 + tid];
      float q = affB[tid] + affB[64 + tid] + affB[128 + tid] + affB[192 + tid];
      atomicAdd(&ostats[tid], s);
      atomicAdd(&ostats[64 + tid], q);
    }
  }
}

// ---------------------------------------------------------------------------
// GAT aggregation (half-wave pairing, 8-pair unroll; at its random-line
// gather floor ~3.5 TB/s — r10/r11 measured). Output fp16 (g16).
// ---------------------------------------------------------------------------
__global__ __launch_bounds__(256) void k_agg(const int* __restrict__ rowptr,
                                             const unsigned short* __restrict__ csr16,
                                             const unsigned short* __restrict__ feat16,
                                             const float* __restrict__ el,
                                             const float* __restrict__ er, const float* __restrict__ gatb,
                                             unsigned short* __restrict__ g16, int n) {
  int v = blockIdx.x * 4 + (threadIdx.x >> 6);
  if (v >= n) return;
  int lane = threadIdx.x & 63;
  int grp = lane >> 5;
  int sub = lane & 31;
  int head = sub >> 4;
  int beg = rowptr[v], end = rowptr[v + 1];
  float er0 = er[(size_t)v * 2 + 0], er1 = er[(size_t)v * 2 + 1];
  float s0 = 0.f, s1 = 0.f;
  float a0 = 0.f, a1 = 0.f, a2 = 0.f, a3 = 0.f;
  const char* fb = (const char*)feat16;
  int sub8 = sub * 8;
  for (int base = beg; base < end; base += 64) {
    int nch = min(64, end - base);
    int uoff_l = 0;
    float w0_l = 0.f, w1_l = 0.f;
    if (base + lane < end) {
      int u = csr16[base + lane];
      uoff_l = u * 256;
      float2 tt = *(const float2*)&el[(size_t)u * 2];
      float e0 = tt.x + er0, e1 = tt.y + er1;
      e0 = (e0 > 0.f) ? e0 : 0.2f * e0;
      e1 = (e1 > 0.f) ? e1 : 0.2f * e1;
      w0_l = __expf(e0);
      w1_l = __expf(e1);
      s0 += w0_l;
      s1 += w1_l;
    }
    int i = 0;
    for (; i + 16 <= nch; i += 16) {
      uint2 q[8];
#pragma unroll
      for (int p = 0; p < 8; ++p) {
        int e = i + 2 * p + grp;
        int uo = __shfl(uoff_l, e);
        q[p] = *(const uint2*)(fb + (size_t)(unsigned)uo + sub8);
      }
#pragma unroll
      for (int p = 0; p < 8; ++p) {
        int e = i + 2 * p + grp;
        float wa = __shfl(w0_l, e);
        float wb = __shfl(w1_l, e);
        float wgt = head ? wb : wa;
        float2 fx = h2f2(q[p].x);
        float2 fy = h2f2(q[p].y);
        a0 += wgt * fx.x;
        a1 += wgt * fx.y;
        a2 += wgt * fy.x;
        a3 += wgt * fy.y;
      }
    }
    for (; i + 8 <= nch; i += 8) {
      uint2 q[4];
#pragma unroll
      for (int p = 0; p < 4; ++p) {
        int e = i + 2 * p + grp;
        int uo = __shfl(uoff_l, e);
        q[p] = *(const uint2*)(fb + (size_t)(unsigned)uo + sub8);
      }
#pragma unroll
      for (int p = 0; p < 4; ++p) {
        int e = i + 2 * p + grp;
        float wa = __shfl(w0_l, e);
        float wb = __shfl(w1_l, e);
        float wgt = head ? wb : wa;
        float2 fx = h2f2(q[p].x);
        float2 fy = h2f2(q[p].y);
        a0 += wgt * fx.x;
        a1 += wgt * fx.y;
        a2 += wgt * fy.x;
        a3 += wgt * fy.y;
      }
    }
    for (; i < nch; i += 2) {
      int e = i + grp;
      int ec = min(e, nch - 1);
      int uo = __shfl(uoff_l, ec);
      float wa = __shfl(w0_l, ec);
      float wb = __shfl(w1_l, ec);
      float wgt = head ? wb : wa;
      if (e >= nch) wgt = 0.f;
      uint2 q = *(const uint2*)(fb + (size_t)(unsigned)uo + sub8);
      float2 fx = h2f2(q.x);
      float2 fy = h2f2(q.y);
      a0 += wgt * fx.x;
      a1 += wgt * fx.y;
      a2 += wgt * fy.x;
      a3 += wgt * fy.y;
    }
  }
  a0 += __shfl_xor(a0, 32, 64);
  a1 += __shfl_xor(a1, 32, 64);
  a2 += __shfl_xor(a2, 32, 64);
  a3 += __shfl_xor(a3, 32, 64);
  for (int o = 32; o > 0; o >>= 1) {
    s0 += __shfl_xor(s0, o, 64);
    s1 += __shfl_xor(s1, o, 64);
  }
  if (lane < 32) {
    float s = head ? s1 : s0;
    float inv = (end > beg) ? 1.f / s : 0.f;
    int c = 4 * sub;
    ushort4 o4;
    o4.x = f2h(a0 * inv + gatb[c]);
    o4.y = f2h(a1 * inv + gatb[c + 1]);
    o4.z = f2h(a2 * inv + gatb[c + 2]);
    o4.w = f2h(a3 * inv + gatb[c + 3]);
    *(ushort4*)&g16[(size_t)v * 128 + c] = o4;
  }
}

// ---------------------------------------------------------------------------
// column stats (sum, sumsq) over an fp16 matrix. C divides 256.
// ---------------------------------------------------------------------------
__global__ __launch_bounds__(256) void k_colstats16(const unsigned short* __restrict__ Z, int pitch,
                                                    int C, int M, float* __restrict__ stats) {
  __shared__ float ls[256];
  __shared__ float lq[256];
  int t = threadIdx.x;
  int c = t % C;
  int rpb = 256 / C;
  int r = blockIdx.x * rpb + t / C;
  int stride = gridDim.x * rpb;
  float s = 0.f, q = 0.f;
  const _Float16* Zh = (const _Float16*)Z;
  for (; r < M; r += stride) {
    float v = (float)Zh[(size_t)r * pitch + c];
    s += v;
    q += v * v;
  }
  ls[t] = s;
  lq[t] = q;
  __syncthreads();
  if (t < C) {
    for (int i = 1; i < rpb; ++i) {
      s += ls[t + i * C];
      q += lq[t + i * C];
    }
    atomicAdd(&stats[c], s);
    atomicAdd(&stats[C + c], q);
  }
}

// bn2 apply (last layer only — earlier layers fused into next fc's staging)
__global__ __launch_bounds__(256) void k_bnapply(const float* __restrict__ u, const float* __restrict__ stats,
                                                 const float* __restrict__ gam, const float* __restrict__ bet,
                                                 unsigned short* __restrict__ yout, int n, float invM) {
  int idx = blockIdx.x * 256 + threadIdx.x;
  if (idx >= n * 16) return;
  int r = idx >> 4, c4 = (idx & 15) * 4;
  float4 uu = *(const float4*)&u[(size_t)r * 64 + c4];
  float vv[4] = {uu.x, uu.y, uu.z, uu.w};
  ushort4 o;
  unsigned short* op = (unsigned short*)&o;
#pragma unroll
  for (int j = 0; j < 4; ++j) {
    int c = c4 + j;
    float mean = stats[c] * invM;
    float var = stats[64 + c] * invM - mean * mean;
    float a = gam[c] * rsqrtf(var + BN_EPS);
    float b = bet[c] - mean * a;
    op[j] = f2h(a * vv[j] + b);
  }
  *(ushort4*)&yout[(size_t)r * 256 + c4] = o;
}

// final: out[n] = sum_j relu(bn(y[n,j])) * w2[j]. One wave per row.
__global__ __launch_bounds__(256) void k_final(const float* __restrict__ y, const float* __restrict__ stats,
                                               const float* __restrict__ gam, const float* __restrict__ bet,
                                               const float* __restrict__ w2, float* __restrict__ out, int n,
                                               float invM) {
  int v = blockIdx.x * 4 + (threadIdx.x >> 6);
  if (v >= n) return;
  int lane = threadIdx.x & 63;
  float mean = stats[lane] * invM;
  float var = stats[64 + lane] * invM - mean * mean;
  float a = gam[lane] * rsqrtf(var + BN_EPS);
  float b = bet[lane] - mean * a;
  float h = a * y[(size_t)v * 64 + lane] + b;
  h = fmaxf(h, 0.f) * w2[lane];
  for (int o = 32; o > 0; o >>= 1) h += __shfl_down(h, o, 64);
  if (lane == 0) out[v] = h;
}

// ---------------------------------------------------------------------------
extern "C" void kernel_launch(void* const* d_in, const int* in_sizes, int n_in,
                              void* d_out, int out_size, void* d_ws, size_t ws_size,
                              hipStream_t stream) {
  const float* x = (const float*)d_in[0];
  const int* src = (const int*)d_in[1];
  const int* dst = (const int*)d_in[2];
  const float* emb_w = (const float*)d_in[3];
  const float* emb_b = (const float*)d_in[4];
  const float* fc_w = (const float*)d_in[5];
  const float* attn_l = (const float*)d_in[6];
  const float* attn_r = (const float*)d_in[7];
  const float* gat_b = (const float*)d_in[8];
  const float* bn1_g = (const float*)d_in[9];
  const float* bn1_b = (const float*)d_in[10];
  const float* ff_w1 = (const float*)d_in[11];
  const float* ff_b1 = (const float*)d_in[12];
  const float* ff_w2 = (const float*)d_in[13];
  const float* ff_b2 = (const float*)d_in[14];
  const float* bn2_g = (const float*)d_in[15];
  const float* bn2_b = (const float*)d_in[16];
  const float* mlp_w1 = (const float*)d_in[17];
  const float* mlp_bn_g = (const float*)d_in[18];
  const float* mlp_bn_b = (const float*)d_in[19];
  const float* mlp_w2 = (const float*)d_in[20];
  float* out = (float*)d_out;
  (void)n_in;
  (void)out_size;

  const int n = in_sizes[0] / 64;  // 50000
  const int E = in_sizes[1];       // 1600000
  const int NL = 3;
  const int nbuk = (n + 127) >> 7;

  char* wsb = (char*)d_ws;
  size_t off = 0;
  auto alloc = [&](size_t bytes) {
    size_t o = off;
    off = (off + bytes + 255) & ~(size_t)255;
    return o;
  };
  size_t o_bcnt = alloc((size_t)512 * 4);
  size_t o_stats = alloc(1280 * 4);
  size_t zero_bytes = off;
  size_t o_rowptr = alloc((size_t)(n + 1) * 4);
  size_t o_bcur = alloc((size_t)512 * 4);
  size_t o_bbase = alloc((size_t)512 * 4);
  size_t o_csr = alloc((size_t)E * 2);
  size_t o_pairs = alloc((size_t)E * 4);
  size_t o_feat = alloc((size_t)n * 128 * 2);      // feat16 fp16
  size_t o_u = alloc((size_t)n * 64 * 4);          // u fp32 (fc reads u while writing feat16)
  size_t o_g = alloc((size_t)n * 128 * 2);         // g16 fp16
  size_t o_t = alloc((size_t)n * 224 * 2 + 256);   // t16, pitch 224 halves
  size_t o_xs = alloc((size_t)n * 256 * 2);        // xs16 concat [n,256] fp16
  size_t o_el = alloc((size_t)n * 2 * 4);
  size_t o_er = alloc((size_t)n * 2 * 4);
  const int n_emb = 64 * 64;
  const int n_fc = NL * 128 * 64;
  const int n_w2rows = NL * 64;
  const int n_mlp = 64 * 256;
  size_t o_embw = alloc((size_t)n_emb * 2);
  size_t o_fcw = alloc((size_t)n_fc * 2);
  size_t o_w2w = alloc((size_t)n_w2rows * 224 * 2);
  size_t o_mlpw = alloc((size_t)n_mlp * 2);
  size_t o_w1f = alloc((size_t)218 * 128 * 2);
  size_t o_b1p = alloc((size_t)224 * 4);
  if (off > ws_size) return;

  int* bcnt = (int*)(wsb + o_bcnt);
  float* stats = (float*)(wsb + o_stats);
  int* rowptr = (int*)(wsb + o_rowptr);
  int* bcur = (int*)(wsb + o_bcur);
  int* bbase = (int*)(wsb + o_bbase);
  unsigned short* csr16 = (unsigned short*)(wsb + o_csr);
  unsigned int* pairs = (unsigned int*)(wsb + o_pairs);
  unsigned short* feat16 = (unsigned short*)(wsb + o_feat);
  float* u = (float*)(wsb + o_u);
  unsigned short* g16 = (unsigned short*)(wsb + o_g);
  unsigned short* t16 = (unsigned short*)(wsb + o_t);
  unsigned short* xs16 = (unsigned short*)(wsb + o_xs);
  float* el = (float*)(wsb + o_el);
  float* er = (float*)(wsb + o_er);
  unsigned short* embw16 = (unsigned short*)(wsb + o_embw);
  unsigned short* fcw16 = (unsigned short*)(wsb + o_fcw);
  unsigned short* w2w16 = (unsigned short*)(wsb + o_w2w);
  unsigned short* mlpw16 = (unsigned short*)(wsb + o_mlpw);
  unsigned short* w1f16 = (unsigned short*)(wsb + o_w1f);
  float* b1p = (float*)(wsb + o_b1p);

  hipMemsetAsync(d_ws, 0, zero_bytes, stream);

  int gchunk = (E + CHUNK - 1) / CHUNK;
  k_bcount<<<gchunk, 256, 0, stream>>>(dst, bcnt, E);
  k_bscan<<<1, 512, 0, stream>>>(bcnt, bcur, bbase, nbuk);
  k_bucket<<<gchunk, 256, 0, stream>>>(src, dst, bcur, pairs, E);
  k_place<<<nbuk, 256, 0, stream>>>(bbase, pairs, csr16, rowptr, n, nbuk, E);

  int cvt_total = n_emb + n_fc + n_w2rows * 224 + n_mlp;
  k_cvtw<<<(cvt_total + 255) / 256, 256, 0, stream>>>(emb_w, fc_w, ff_w2, mlp_w1,
                                                      embw16, fcw16, w2w16, mlpw16,
                                                      n_emb, n_fc, n_w2rows, n_mlp);

  int gm = (n + 127) / 128;
  float invM = 1.f / (float)n;

  // embedding -> xs16[:, 0:64)   (X fp32, W fp16, Y fp16)
  k_gemm<<<dim3(gm, 1), 256, 0, stream>>>(x, 64, embw16, 64, emb_b, nullptr, nullptr, nullptr, invM,
                                          xs16, 256, n, 64, 64, 4 | 64,
                                          nullptr, nullptr, nullptr, nullptr, nullptr, nullptr);

  for (int l = 0; l < NL; ++l) {
    float* sbn1 = stats + l * 384;
    float* sbn2 = stats + l * 384 + 256;
    // fc: feat16 = h @ fc_w^T + fused attn logits (grid (gm,2), 64 cols/block).
    // l==0: X = xs16 slice0 (fp16). l>0: X = u + bn2 affine (fused bn2-apply),
    // blockIdx.y==0 side-writes the affined fp16 tile into xs16 slice l.
    if (l == 0) {
      k_gemm<<<dim3(gm, 2), 256, 0, stream>>>(xs16, 256, fcw16, 64,
                                              nullptr, nullptr, nullptr, nullptr, invM,
                                              feat16, 128, n, 64, 128, 4 | 8 | 32 | 64,
                                              nullptr, attn_l, attn_r, el, er, nullptr);
    } else {
      float* sprev = stats + (l - 1) * 384 + 256;
      k_gemm<<<dim3(gm, 2), 256, 0, stream>>>(u, 64, fcw16 + (size_t)l * 128 * 64, 64,
                                              nullptr, sprev, bn2_g + (l - 1) * 64, bn2_b + (l - 1) * 64,
                                              invM, feat16, 128, n, 64, 128, 2 | 4 | 32 | 64,
                                              nullptr, attn_l + l * 128, attn_r + l * 128, el, er,
                                              xs16 + 64 * l);
    }
    k_agg<<<(n + 3) / 4, 256, 0, stream>>>(rowptr, csr16, feat16, el, er, gat_b + l * 128, g16, n);
    k_colstats16<<<512, 256, 0, stream>>>(g16, 128, 128, n, sbn1);
    k_foldw1<<<(218 + 3) / 4, 256, 0, stream>>>(ff_w1 + (size_t)l * 218 * 128, ff_b1 + l * 218,
                                                sbn1, bn1_g + l * 128, bn1_b + l * 128, invM,
                                                w1f16, b1p, 218, 128);
    // ff1: t16 = relu(g16 @ W1'^T + b1')   (grid (gm,4), r12 shape)
    k_gemm<<<dim3(gm, 4), 256, 0, stream>>>(g16, 128, w1f16, 128, b1p,
                                            nullptr, nullptr, nullptr, invM,
                                            t16, 224, n, 128, 218, 1 | 4 | 8 | 64,
                                            nullptr, nullptr, nullptr, nullptr, nullptr, nullptr);
    // ff2: u = t16 @ W2^T + b2   (fused bn2 col-stats)
    k_gemm<<<dim3(gm, 1), 256, 0, stream>>>(t16, 224, w2w16 + (size_t)l * 64 * 224, 224, ff_b2 + l * 64,
                                            nullptr, nullptr, nullptr, invM,
                                            u, 64, n, 218, 64, 8 | 16 | 64,
                                            sbn2, nullptr, nullptr, nullptr, nullptr, nullptr);
    if (l == NL - 1) {
      k_bnapply<<<(n * 16 + 255) / 256, 256, 0, stream>>>(u, sbn2, bn2_g + l * 64, bn2_b + l * 64,
                                                          xs16 + 64 * (l + 1), n, invM);
    }
  }

  float* smlp = stats + 1152;
  // mlp: u = xs16 @ mlp_w1^T   (fused col-stats)
  k_gemm<<<dim3(gm, 1), 256, 0, stream>>>(xs16, 256, mlpw16, 256, nullptr, nullptr, nullptr, nullptr,
                                          invM, u, 64, n, 256, 64, 8 | 16 | 64,
                                          smlp, nullptr, nullptr, nullptr, nullptr, nullptr);
  k_final<<<(n + 3) / 4, 256, 0, stream>>>(u, smlp, mlp_bn_g, mlp_bn_b, mlp_w2, out, n, invM);
}

// Round 15
// 663.686 us; speedup vs baseline: 1.0789x; 1.0606x over previous
//
#include <hip/hip_runtime.h>
#include <cstdint>

#define BN_EPS 1e-5f

typedef _Float16 f16x8 __attribute__((ext_vector_type(8)));
typedef _Float16 f16x2 __attribute__((ext_vector_type(2)));
typedef float f32x4 __attribute__((ext_vector_type(4)));

__device__ __forceinline__ unsigned short f2h(float f) {
  _Float16 h = (_Float16)f;
  return *(unsigned short*)&h;
}
__device__ __forceinline__ float2 h2f2(unsigned int q) {
  f16x2 h = __builtin_bit_cast(f16x2, q);
  return make_float2((float)h.x, (float)h.y);
}

// ---------------------------------------------------------------------------
// CSR build (by dst), once per call — bucket-first, no per-node atomics.
// ---------------------------------------------------------------------------
#define CHUNK 8192
#define MAXBUK 512

__global__ __launch_bounds__(256) void k_bcount(const int* __restrict__ dst, int* __restrict__ bcnt, int E) {
  __shared__ int hist[MAXBUK];
  int tid = threadIdx.x;
  int base = blockIdx.x * CHUNK;
  int cnt = min(CHUNK, E - base);
  if (cnt <= 0) return;
  for (int b = tid; b < MAXBUK; b += 256) hist[b] = 0;
  __syncthreads();
  for (int i = tid; i < cnt; i += 256) atomicAdd(&hist[dst[base + i] >> 7], 1);
  __syncthreads();
  for (int b = tid; b < MAXBUK; b += 256) {
    int c = hist[b];
    if (c > 0) atomicAdd(&bcnt[b], c);
  }
}

__global__ __launch_bounds__(512) void k_bscan(const int* __restrict__ bcnt, int* __restrict__ bcur,
                                               int* __restrict__ bbase, int nbuk) {
  __shared__ int sh[512];
  int t = threadIdx.x;
  int v = (t < nbuk) ? bcnt[t] : 0;
  sh[t] = v;
  __syncthreads();
  for (int off = 1; off < 512; off <<= 1) {
    int u = (t >= off) ? sh[t - off] : 0;
    __syncthreads();
    sh[t] += u;
    __syncthreads();
  }
  if (t < nbuk) {
    int excl = sh[t] - v;
    bcur[t] = excl;
    bbase[t] = excl;
  }
}

__global__ __launch_bounds__(256) void k_bucket(const int* __restrict__ src, const int* __restrict__ dst,
                                                int* __restrict__ bcur, unsigned int* __restrict__ pairs,
                                                int E) {
  __shared__ unsigned int ep[CHUNK];
  __shared__ int bcnt[MAXBUK];
  __shared__ int gbase[MAXBUK];
  __shared__ int rcnt[MAXBUK];
  int tid = threadIdx.x;
  int base = blockIdx.x * CHUNK;
  int cnt = min(CHUNK, E - base);
  if (cnt <= 0) return;

  for (int b = tid; b < MAXBUK; b += 256) { bcnt[b] = 0; rcnt[b] = 0; }
  __syncthreads();
  for (int i = tid; i < cnt; i += 256) {
    int d = dst[base + i];
    int s = src[base + i];
    unsigned int pk = ((unsigned)(d >> 7) << 23) | ((unsigned)(d & 127) << 16) | (unsigned)s;
    ep[i] = pk;
    atomicAdd(&bcnt[d >> 7], 1);
  }
  __syncthreads();
  for (int b = tid; b < MAXBUK; b += 256) {
    int c = bcnt[b];
    gbase[b] = (c > 0) ? atomicAdd(&bcur[b], c) : 0;
  }
  __syncthreads();
  for (int i = tid; i < cnt; i += 256) {
    unsigned int pk = ep[i];
    int bk = pk >> 23;
    int r = atomicAdd(&rcnt[bk], 1);
    pairs[gbase[bk] + r] = pk & 0x007FFFFFu;
  }
}

#define PLACE_CAP 24576

__global__ __launch_bounds__(256) void k_place(const int* __restrict__ bbase,
                                               const unsigned int* __restrict__ pairs,
                                               unsigned short* __restrict__ csr16,
                                               int* __restrict__ rowptr, int n, int nbuk, int E) {
  __shared__ unsigned short stage[PLACE_CAP];
  __shared__ int nc[128];
  __shared__ int nstart[128];
  __shared__ int nrun[128];
  int tid = threadIdx.x;
  int bk = blockIdx.x;
  int v0 = bk * 128;
  int beg = bbase[bk];
  int end = (bk + 1 < nbuk) ? bbase[bk + 1] : E;
  int cnt = end - beg;
  if (tid < 128) { nc[tid] = 0; nrun[tid] = 0; }
  __syncthreads();
  for (int i = tid; i < cnt; i += 256) atomicAdd(&nc[(pairs[beg + i] >> 16) & 127], 1);
  __syncthreads();
  if (tid < 128) nstart[tid] = nc[tid];
  __syncthreads();
  for (int off = 1; off < 128; off <<= 1) {
    int v = (tid < 128 && tid >= off) ? nstart[tid - off] : 0;
    __syncthreads();
    if (tid < 128) nstart[tid] += v;
    __syncthreads();
  }
  if (tid < 128) nstart[tid] -= nc[tid];
  __syncthreads();
  if (tid < 128 && v0 + tid < n) rowptr[v0 + tid] = beg + nstart[tid];
  if (bk == nbuk - 1 && tid == 0) rowptr[n] = E;
  if (cnt <= 0) return;
  if (cnt <= PLACE_CAP) {
    for (int i = tid; i < cnt; i += 256) {
      unsigned int p = pairs[beg + i];
      int dlow = (p >> 16) & 127;
      int r = atomicAdd(&nrun[dlow], 1);
      stage[nstart[dlow] + r] = (unsigned short)(p & 0xFFFF);
    }
    __syncthreads();
    for (int i = tid; i < cnt; i += 256) csr16[beg + i] = stage[i];
  } else {
    for (int i = tid; i < cnt; i += 256) {
      unsigned int p = pairs[beg + i];
      int dlow = (p >> 16) & 127;
      int r = atomicAdd(&nrun[dlow], 1);
      csr16[beg + nstart[dlow] + r] = (unsigned short)(p & 0xFFFF);
    }
  }
}

// ---------------------------------------------------------------------------
// one-shot fp32 -> fp16 conversion of all static weights (per call).
// ff_w2 rows padded 218 -> 224 halves (zero fill).
// ---------------------------------------------------------------------------
__global__ __launch_bounds__(256) void k_cvtw(
    const float* __restrict__ emb, const float* __restrict__ fc,
    const float* __restrict__ w2, const float* __restrict__ mlp,
    unsigned short* __restrict__ o_emb, unsigned short* __restrict__ o_fc,
    unsigned short* __restrict__ o_w2, unsigned short* __restrict__ o_mlp,
    int n_emb, int n_fc, int n_w2rows, int n_mlp) {
  int idx = blockIdx.x * 256 + threadIdx.x;
  if (idx < n_emb) { o_emb[idx] = f2h(emb[idx]); return; }
  idx -= n_emb;
  if (idx < n_fc) { o_fc[idx] = f2h(fc[idx]); return; }
  idx -= n_fc;
  int w2tot = n_w2rows * 224;
  if (idx < w2tot) {
    int r = idx / 224, c = idx - r * 224;
    o_w2[idx] = f2h((c < 218) ? w2[r * 218 + c] : 0.f);
    return;
  }
  idx -= w2tot;
  if (idx < n_mlp) o_mlp[idx] = f2h(mlp[idx]);
}

// ---------------------------------------------------------------------------
// fold bn1 affine into ff1 weights (per layer, after bn1 stats).
// ---------------------------------------------------------------------------
__global__ __launch_bounds__(256) void k_foldw1(const float* __restrict__ W1, const float* __restrict__ b1,
                                                const float* __restrict__ stats, const float* __restrict__ gam,
                                                const float* __restrict__ bet, float invM,
                                                unsigned short* __restrict__ W16, float* __restrict__ b1p,
                                                int rows, int K) {
  __shared__ float aA[128];
  __shared__ float aB[128];
  int tid = threadIdx.x;
  if (tid < K) {
    float mean = stats[tid] * invM;
    float var = stats[K + tid] * invM - mean * mean;
    float a = gam[tid] * rsqrtf(var + BN_EPS);
    aA[tid] = a;
    aB[tid] = bet[tid] - mean * a;
  }
  __syncthreads();
  int w = tid >> 6, lane = tid & 63;
  int i = blockIdx.x * 4 + w;
  if (i >= rows) return;
  const float* wr = W1 + (size_t)i * K;
  float dot = 0.f;
  for (int k = lane; k < K; k += 64) {
    float wv = wr[k];
    W16[(size_t)i * K + k] = f2h(wv * aA[k]);
    dot += wv * aB[k];
  }
  for (int o = 32; o > 0; o >>= 1) dot += __shfl_down(dot, o, 64);
  if (lane == 0) b1p[i] = b1[i] + dot;
}

// ---------------------------------------------------------------------------
// fp16-MFMA GEMM (128 rows x 64 cols, 256 threads = 4 waves).
// flags: bit0 relu | bit1 input BN affine (fp32 X only) | bit2 Y fp16 |
//        bit3 X fp16 | bit4 fused col-stats (COLS<=64, grid.y=1) |
//        bit5 fused attn logits (COLS=128, head=blockIdx.y) | bit6 W fp16
// ---------------------------------------------------------------------------
__global__ __launch_bounds__(256) void k_gemm(
    const void* __restrict__ Xv, int xpitch,
    const void* __restrict__ Wv, int wpitch,
    const float* __restrict__ bias,
    const float* __restrict__ stats, const float* __restrict__ gamma, const float* __restrict__ beta,
    float invM, void* __restrict__ Yv, int ypitch,
    int M, int KK, int COLS, int flags,
    float* __restrict__ ostats,
    const float* __restrict__ al, const float* __restrict__ ar,
    float* __restrict__ el, float* __restrict__ er) {
  __shared__ unsigned short Xs[128 * 72];
  __shared__ unsigned short Ws[64 * 72];
  __shared__ float affA[256];
  __shared__ float affB[256];

  int tid = threadIdx.x;
  int m0 = blockIdx.x * 128;
  int c0 = blockIdx.y * 64;
  const bool relu = (flags & 1) != 0;
  const bool aff = (flags & 2) != 0;
  const bool yf16 = (flags & 4) != 0;
  const bool xf16 = (flags & 8) != 0;
  const bool fstat = (flags & 16) != 0;
  const bool fattn = (flags & 32) != 0;
  const bool wf16 = (flags & 64) != 0;

  if (aff) {
    if (tid < KK && tid < 256) {
      float mean = stats[tid] * invM;
      float var = stats[KK + tid] * invM - mean * mean;
      float a = gamma[tid] * rsqrtf(var + BN_EPS);
      affA[tid] = a;
      affB[tid] = beta[tid] - mean * a;
    }
    __syncthreads();
  }

  int w = tid >> 6;
  int lane = tid & 63;
  int l15 = lane & 15;
  int lhi = lane >> 4;

  f32x4 acc[2][4];
#pragma unroll
  for (int i = 0; i < 2; ++i)
#pragma unroll
    for (int j = 0; j < 4; ++j) acc[i][j] = (f32x4){0.f, 0.f, 0.f, 0.f};

  for (int kt = 0; kt < KK; kt += 64) {
    // ---- stage X tile (128 x 64 halves)
    if (xf16) {
      const unsigned short* X16 = (const unsigned short*)Xv;
#pragma unroll
      for (int p = 0; p < 4; ++p) {
        int idx = p * 256 + tid;
        int r = idx >> 3;
        int k8 = (idx & 7) * 8;
        int gr = m0 + r, gk = kt + k8;
        if (gr < M && gk + 8 <= KK) {
          *(uint4*)&Xs[r * 72 + k8] = *(const uint4*)(X16 + (size_t)gr * xpitch + gk);
        } else {
#pragma unroll
          for (int j = 0; j < 8; ++j)
            Xs[r * 72 + k8 + j] =
                (gr < M && gk + j < KK) ? X16[(size_t)gr * xpitch + gk + j] : (unsigned short)0;
        }
      }
    } else {
      const float* X = (const float*)Xv;
      int rb = tid >> 4;
      int c4 = (tid & 15) * 4;
#pragma unroll
      for (int p = 0; p < 8; ++p) {
        int r = p * 16 + rb;
        int gr = m0 + r;
        int gk = kt + c4;
        float4 v = make_float4(0.f, 0.f, 0.f, 0.f);
        if (gr < M) {
          const float* px = X + (size_t)gr * xpitch;
          if (gk + 3 < KK) {
            v = *(const float4*)(px + gk);
            if (aff) {
              v.x = v.x * affA[gk] + affB[gk];
              v.y = v.y * affA[gk + 1] + affB[gk + 1];
              v.z = v.z * affA[gk + 2] + affB[gk + 2];
              v.w = v.w * affA[gk + 3] + affB[gk + 3];
            }
          } else if (gk < KK) {
            float tmp[4];
#pragma unroll
            for (int j = 0; j < 4; ++j) {
              float t = 0.f;
              if (gk + j < KK) {
                t = px[gk + j];
                if (aff) t = t * affA[gk + j] + affB[gk + j];
              }
              tmp[j] = t;
            }
            v.x = tmp[0]; v.y = tmp[1]; v.z = tmp[2]; v.w = tmp[3];
          }
        }
        ushort4 o = make_ushort4(f2h(v.x), f2h(v.y), f2h(v.z), f2h(v.w));
        *(ushort4*)&Xs[r * 72 + c4] = o;
      }
    }
    // ---- stage W tile (64 cols x 64 k)
    if (wf16) {
      const unsigned short* W16 = (const unsigned short*)Wv;
#pragma unroll
      for (int p = 0; p < 4; ++p) {
        int idx = p * 256 + tid;
        int c = idx >> 4;
        int k4 = (idx & 15) * 4;
        int gc = c0 + c, gk = kt + k4;
        uint2 val = make_uint2(0u, 0u);
        if (gc < COLS && gk + 4 <= wpitch) {
          val = *(const uint2*)(W16 + (size_t)gc * wpitch + gk);
        }
        *(uint2*)&Ws[c * 72 + k4] = val;
      }
    } else {
      const float* W = (const float*)Wv;
      int cb = tid >> 5;
      int k2 = (tid & 31) * 2;
#pragma unroll
      for (int p = 0; p < 8; ++p) {
        int c = p * 8 + cb;
        int gc = c0 + c;
        int gk = kt + k2;
        float2 v = make_float2(0.f, 0.f);
        if (gc < COLS) {
          const float* pw = W + (size_t)gc * wpitch;
          if (gk + 1 < KK) {
            v = *(const float2*)(pw + gk);
          } else if (gk < KK) {
            v.x = pw[gk];
          }
        }
        ushort2 o = make_ushort2(f2h(v.x), f2h(v.y));
        *(ushort2*)&Ws[c * 72 + k2] = o;
      }
    }
    __syncthreads();

#pragma unroll
    for (int ks = 0; ks < 64; ks += 32) {
      f16x8 a0 = *(const f16x8*)&Xs[(32 * w + l15) * 72 + ks + lhi * 8];
      f16x8 a1 = *(const f16x8*)&Xs[(32 * w + 16 + l15) * 72 + ks + lhi * 8];
#pragma unroll
      for (int ct = 0; ct < 4; ++ct) {
        f16x8 b = *(const f16x8*)&Ws[(16 * ct + l15) * 72 + ks + lhi * 8];
        acc[0][ct] = __builtin_amdgcn_mfma_f32_16x16x32_f16(a0, b, acc[0][ct], 0, 0, 0);
        acc[1][ct] = __builtin_amdgcn_mfma_f32_16x16x32_f16(a1, b, acc[1][ct], 0, 0, 0);
      }
    }
    __syncthreads();
  }

  // ---- epilogue
  float sArr[4] = {0.f, 0.f, 0.f, 0.f}, qArr[4] = {0.f, 0.f, 0.f, 0.f};
  float rdl[8], rdr[8];
#pragma unroll
  for (int j = 0; j < 8; ++j) { rdl[j] = 0.f; rdr[j] = 0.f; }

#pragma unroll
  for (int rt = 0; rt < 2; ++rt) {
#pragma unroll
    for (int ct = 0; ct < 4; ++ct) {
      int c = c0 + 16 * ct + l15;
      if (c >= COLS) continue;
      float bv = bias ? bias[c] : 0.f;
      float alc = fattn ? al[c] : 0.f;
      float arc = fattn ? ar[c] : 0.f;
#pragma unroll
      for (int reg = 0; reg < 4; ++reg) {
        int r = m0 + 32 * w + 16 * rt + lhi * 4 + reg;
        if (r >= M) continue;
        float vv = acc[rt][ct][reg] + bv;
        if (relu) vv = fmaxf(vv, 0.f);
        if (yf16)
          ((unsigned short*)Yv)[(size_t)r * ypitch + c] = f2h(vv);
        else
          ((float*)Yv)[(size_t)r * ypitch + c] = vv;
        if (fstat) { sArr[ct] += vv; qArr[ct] += vv * vv; }
        if (fattn) { rdl[rt * 4 + reg] += vv * alc; rdr[rt * 4 + reg] += vv * arc; }
      }
    }
  }

  if (fattn) {
#pragma unroll
    for (int j = 0; j < 8; ++j) {
      float a = rdl[j], b = rdr[j];
      a += __shfl_xor(a, 1, 64); b += __shfl_xor(b, 1, 64);
      a += __shfl_xor(a, 2, 64); b += __shfl_xor(b, 2, 64);
      a += __shfl_xor(a, 4, 64); b += __shfl_xor(b, 4, 64);
      a += __shfl_xor(a, 8, 64); b += __shfl_xor(b, 8, 64);
      rdl[j] = a; rdr[j] = b;
    }
    if (l15 == 0) {
      int hy = blockIdx.y;
#pragma unroll
      for (int j = 0; j < 8; ++j) {
        int r = m0 + 32 * w + 16 * (j >> 2) + lhi * 4 + (j & 3);
        if (r < M) {
          el[(size_t)r * 2 + hy] = rdl[j];
          er[(size_t)r * 2 + hy] = rdr[j];
        }
      }
    }
  }

  if (fstat) {
#pragma unroll
    for (int ct = 0; ct < 4; ++ct) {
      float s = sArr[ct], q = qArr[ct];
      s += __shfl_xor(s, 16, 64); q += __shfl_xor(q, 16, 64);
      s += __shfl_xor(s, 32, 64); q += __shfl_xor(q, 32, 64);
      if (lhi == 0) {
        affA[w * 64 + ct * 16 + l15] = s;
        affB[w * 64 + ct * 16 + l15] = q;
      }
    }
    __syncthreads();
    if (tid < 64) {
      float s = affA[tid] + affA[64 + tid] + affA[128 + tid] + affA[192 + tid];
      float q = affB[tid] + affB[64 + tid] + affB[128 + tid] + affB[192 + tid];
      atomicAdd(&ostats[tid], s);
      atomicAdd(&ostats[64 + tid], q);
    }
  }
}

// ---------------------------------------------------------------------------
// GAT aggregation (half-wave pairing, 8-pair unroll; at its random-line
// gather floor ~3.5 TB/s — r10/r11 measured). Output fp16 (g16).
// ---------------------------------------------------------------------------
__global__ __launch_bounds__(256) void k_agg(const int* __restrict__ rowptr,
                                             const unsigned short* __restrict__ csr16,
                                             const unsigned short* __restrict__ feat16,
                                             const float* __restrict__ el,
                                             const float* __restrict__ er, const float* __restrict__ gatb,
                                             unsigned short* __restrict__ g16, int n) {
  int v = blockIdx.x * 4 + (threadIdx.x >> 6);
  if (v >= n) return;
  int lane = threadIdx.x & 63;
  int grp = lane >> 5;
  int sub = lane & 31;
  int head = sub >> 4;
  int beg = rowptr[v], end = rowptr[v + 1];
  float er0 = er[(size_t)v * 2 + 0], er1 = er[(size_t)v * 2 + 1];
  float s0 = 0.f, s1 = 0.f;
  float a0 = 0.f, a1 = 0.f, a2 = 0.f, a3 = 0.f;
  const char* fb = (const char*)feat16;
  int sub8 = sub * 8;
  for (int base = beg; base < end; base += 64) {
    int nch = min(64, end - base);
    int uoff_l = 0;
    float w0_l = 0.f, w1_l = 0.f;
    if (base + lane < end) {
      int u = csr16[base + lane];
      uoff_l = u * 256;
      float2 tt = *(const float2*)&el[(size_t)u * 2];
      float e0 = tt.x + er0, e1 = tt.y + er1;
      e0 = (e0 > 0.f) ? e0 : 0.2f * e0;
      e1 = (e1 > 0.f) ? e1 : 0.2f * e1;
      w0_l = __expf(e0);
      w1_l = __expf(e1);
      s0 += w0_l;
      s1 += w1_l;
    }
    int i = 0;
    for (; i + 16 <= nch; i += 16) {
      uint2 q[8];
#pragma unroll
      for (int p = 0; p < 8; ++p) {
        int e = i + 2 * p + grp;
        int uo = __shfl(uoff_l, e);
        q[p] = *(const uint2*)(fb + (size_t)(unsigned)uo + sub8);
      }
#pragma unroll
      for (int p = 0; p < 8; ++p) {
        int e = i + 2 * p + grp;
        float wa = __shfl(w0_l, e);
        float wb = __shfl(w1_l, e);
        float wgt = head ? wb : wa;
        float2 fx = h2f2(q[p].x);
        float2 fy = h2f2(q[p].y);
        a0 += wgt * fx.x;
        a1 += wgt * fx.y;
        a2 += wgt * fy.x;
        a3 += wgt * fy.y;
      }
    }
    for (; i + 8 <= nch; i += 8) {
      uint2 q[4];
#pragma unroll
      for (int p = 0; p < 4; ++p) {
        int e = i + 2 * p + grp;
        int uo = __shfl(uoff_l, e);
        q[p] = *(const uint2*)(fb + (size_t)(unsigned)uo + sub8);
      }
#pragma unroll
      for (int p = 0; p < 4; ++p) {
        int e = i + 2 * p + grp;
        float wa = __shfl(w0_l, e);
        float wb = __shfl(w1_l, e);
        float wgt = head ? wb : wa;
        float2 fx = h2f2(q[p].x);
        float2 fy = h2f2(q[p].y);
        a0 += wgt * fx.x;
        a1 += wgt * fx.y;
        a2 += wgt * fy.x;
        a3 += wgt * fy.y;
      }
    }
    for (; i < nch; i += 2) {
      int e = i + grp;
      int ec = min(e, nch - 1);
      int uo = __shfl(uoff_l, ec);
      float wa = __shfl(w0_l, ec);
      float wb = __shfl(w1_l, ec);
      float wgt = head ? wb : wa;
      if (e >= nch) wgt = 0.f;
      uint2 q = *(const uint2*)(fb + (size_t)(unsigned)uo + sub8);
      float2 fx = h2f2(q.x);
      float2 fy = h2f2(q.y);
      a0 += wgt * fx.x;
      a1 += wgt * fx.y;
      a2 += wgt * fy.x;
      a3 += wgt * fy.y;
    }
  }
  a0 += __shfl_xor(a0, 32, 64);
  a1 += __shfl_xor(a1, 32, 64);
  a2 += __shfl_xor(a2, 32, 64);
  a3 += __shfl_xor(a3, 32, 64);
  for (int o = 32; o > 0; o >>= 1) {
    s0 += __shfl_xor(s0, o, 64);
    s1 += __shfl_xor(s1, o, 64);
  }
  if (lane < 32) {
    float s = head ? s1 : s0;
    float inv = (end > beg) ? 1.f / s : 0.f;
    int c = 4 * sub;
    ushort4 o4;
    o4.x = f2h(a0 * inv + gatb[c]);
    o4.y = f2h(a1 * inv + gatb[c + 1]);
    o4.z = f2h(a2 * inv + gatb[c + 2]);
    o4.w = f2h(a3 * inv + gatb[c + 3]);
    *(ushort4*)&g16[(size_t)v * 128 + c] = o4;
  }
}

// ---------------------------------------------------------------------------
// column stats (sum, sumsq) over an fp16 matrix. C divides 256.
// ---------------------------------------------------------------------------
__global__ __launch_bounds__(256) void k_colstats16(const unsigned short* __restrict__ Z, int pitch,
                                                    int C, int M, float* __restrict__ stats) {
  __shared__ float ls[256];
  __shared__ float lq[256];
  int t = threadIdx.x;
  int c = t % C;
  int rpb = 256 / C;
  int r = blockIdx.x * rpb + t / C;
  int stride = gridDim.x * rpb;
  float s = 0.f, q = 0.f;
  const _Float16* Zh = (const _Float16*)Z;
  for (; r < M; r += stride) {
    float v = (float)Zh[(size_t)r * pitch + c];
    s += v;
    q += v * v;
  }
  ls[t] = s;
  lq[t] = q;
  __syncthreads();
  if (t < C) {
    for (int i = 1; i < rpb; ++i) {
      s += ls[t + i * C];
      q += lq[t + i * C];
    }
    atomicAdd(&stats[c], s);
    atomicAdd(&stats[C + c], q);
  }
}

// bn2 apply: xs16[:, coloff..coloff+64) = fp16(a*u + b), 4 cols/thread
__global__ __launch_bounds__(256) void k_bnapply(const float* __restrict__ u, const float* __restrict__ stats,
                                                 const float* __restrict__ gam, const float* __restrict__ bet,
                                                 unsigned short* __restrict__ yout, int n, float invM) {
  int idx = blockIdx.x * 256 + threadIdx.x;
  if (idx >= n * 16) return;
  int r = idx >> 4, c4 = (idx & 15) * 4;
  float4 uu = *(const float4*)&u[(size_t)r * 64 + c4];
  float vv[4] = {uu.x, uu.y, uu.z, uu.w};
  ushort4 o;
  unsigned short* op = (unsigned short*)&o;
#pragma unroll
  for (int j = 0; j < 4; ++j) {
    int c = c4 + j;
    float mean = stats[c] * invM;
    float var = stats[64 + c] * invM - mean * mean;
    float a = gam[c] * rsqrtf(var + BN_EPS);
    float b = bet[c] - mean * a;
    op[j] = f2h(a * vv[j] + b);
  }
  *(ushort4*)&yout[(size_t)r * 256 + c4] = o;
}

// final: out[n] = sum_j relu(bn(y[n,j])) * w2[j]. One wave per row.
__global__ __launch_bounds__(256) void k_final(const float* __restrict__ y, const float* __restrict__ stats,
                                               const float* __restrict__ gam, const float* __restrict__ bet,
                                               const float* __restrict__ w2, float* __restrict__ out, int n,
                                               float invM) {
  int v = blockIdx.x * 4 + (threadIdx.x >> 6);
  if (v >= n) return;
  int lane = threadIdx.x & 63;
  float mean = stats[lane] * invM;
  float var = stats[64 + lane] * invM - mean * mean;
  float a = gam[lane] * rsqrtf(var + BN_EPS);
  float b = bet[lane] - mean * a;
  float h = a * y[(size_t)v * 64 + lane] + b;
  h = fmaxf(h, 0.f) * w2[lane];
  for (int o = 32; o > 0; o >>= 1) h += __shfl_down(h, o, 64);
  if (lane == 0) out[v] = h;
}

// ---------------------------------------------------------------------------
extern "C" void kernel_launch(void* const* d_in, const int* in_sizes, int n_in,
                              void* d_out, int out_size, void* d_ws, size_t ws_size,
                              hipStream_t stream) {
  const float* x = (const float*)d_in[0];
  const int* src = (const int*)d_in[1];
  const int* dst = (const int*)d_in[2];
  const float* emb_w = (const float*)d_in[3];
  const float* emb_b = (const float*)d_in[4];
  const float* fc_w = (const float*)d_in[5];
  const float* attn_l = (const float*)d_in[6];
  const float* attn_r = (const float*)d_in[7];
  const float* gat_b = (const float*)d_in[8];
  const float* bn1_g = (const float*)d_in[9];
  const float* bn1_b = (const float*)d_in[10];
  const float* ff_w1 = (const float*)d_in[11];
  const float* ff_b1 = (const float*)d_in[12];
  const float* ff_w2 = (const float*)d_in[13];
  const float* ff_b2 = (const float*)d_in[14];
  const float* bn2_g = (const float*)d_in[15];
  const float* bn2_b = (const float*)d_in[16];
  const float* mlp_w1 = (const float*)d_in[17];
  const float* mlp_bn_g = (const float*)d_in[18];
  const float* mlp_bn_b = (const float*)d_in[19];
  const float* mlp_w2 = (const float*)d_in[20];
  float* out = (float*)d_out;
  (void)n_in;
  (void)out_size;

  const int n = in_sizes[0] / 64;  // 50000
  const int E = in_sizes[1];       // 1600000
  const int NL = 3;
  const int nbuk = (n + 127) >> 7;

  char* wsb = (char*)d_ws;
  size_t off = 0;
  auto alloc = [&](size_t bytes) {
    size_t o = off;
    off = (off + bytes + 255) & ~(size_t)255;
    return o;
  };
  size_t o_bcnt = alloc((size_t)512 * 4);
  size_t o_stats = alloc(1280 * 4);
  size_t zero_bytes = off;
  size_t o_rowptr = alloc((size_t)(n + 1) * 4);
  size_t o_bcur = alloc((size_t)512 * 4);
  size_t o_bbase = alloc((size_t)512 * 4);
  size_t o_csr = alloc((size_t)E * 2);
  size_t o_pairs = alloc((size_t)E * 4);
  size_t o_feat = alloc((size_t)n * 64 * 4);       // feat16 [n,128]x2B == u fp32 [n,64]x4B (aliased)
  size_t o_g = alloc((size_t)n * 128 * 2);         // g16 fp16
  size_t o_t = alloc((size_t)n * 224 * 2 + 256);   // t16, pitch 224 halves
  size_t o_xs = alloc((size_t)n * 256 * 2);        // xs16 concat [n,256] fp16
  size_t o_el = alloc((size_t)n * 2 * 4);
  size_t o_er = alloc((size_t)n * 2 * 4);
  const int n_emb = 64 * 64;
  const int n_fc = NL * 128 * 64;
  const int n_w2rows = NL * 64;
  const int n_mlp = 64 * 256;
  size_t o_embw = alloc((size_t)n_emb * 2);
  size_t o_fcw = alloc((size_t)n_fc * 2);
  size_t o_w2w = alloc((size_t)n_w2rows * 224 * 2);
  size_t o_mlpw = alloc((size_t)n_mlp * 2);
  size_t o_w1f = alloc((size_t)218 * 128 * 2);
  size_t o_b1p = alloc((size_t)224 * 4);
  if (off > ws_size) return;

  int* bcnt = (int*)(wsb + o_bcnt);
  float* stats = (float*)(wsb + o_stats);
  int* rowptr = (int*)(wsb + o_rowptr);
  int* bcur = (int*)(wsb + o_bcur);
  int* bbase = (int*)(wsb + o_bbase);
  unsigned short* csr16 = (unsigned short*)(wsb + o_csr);
  unsigned int* pairs = (unsigned int*)(wsb + o_pairs);
  unsigned short* feat16 = (unsigned short*)(wsb + o_feat);
  unsigned short* g16 = (unsigned short*)(wsb + o_g);
  unsigned short* t16 = (unsigned short*)(wsb + o_t);
  unsigned short* xs16 = (unsigned short*)(wsb + o_xs);
  float* el = (float*)(wsb + o_el);
  float* er = (float*)(wsb + o_er);
  unsigned short* embw16 = (unsigned short*)(wsb + o_embw);
  unsigned short* fcw16 = (unsigned short*)(wsb + o_fcw);
  unsigned short* w2w16 = (unsigned short*)(wsb + o_w2w);
  unsigned short* mlpw16 = (unsigned short*)(wsb + o_mlpw);
  unsigned short* w1f16 = (unsigned short*)(wsb + o_w1f);
  float* b1p = (float*)(wsb + o_b1p);
  float* u = (float*)(wsb + o_feat);  // alias: feat16 dead after k_agg, u born at ff2

  hipMemsetAsync(d_ws, 0, zero_bytes, stream);

  int gchunk = (E + CHUNK - 1) / CHUNK;
  k_bcount<<<gchunk, 256, 0, stream>>>(dst, bcnt, E);
  k_bscan<<<1, 512, 0, stream>>>(bcnt, bcur, bbase, nbuk);
  k_bucket<<<gchunk, 256, 0, stream>>>(src, dst, bcur, pairs, E);
  k_place<<<nbuk, 256, 0, stream>>>(bbase, pairs, csr16, rowptr, n, nbuk, E);

  int cvt_total = n_emb + n_fc + n_w2rows * 224 + n_mlp;
  k_cvtw<<<(cvt_total + 255) / 256, 256, 0, stream>>>(emb_w, fc_w, ff_w2, mlp_w1,
                                                      embw16, fcw16, w2w16, mlpw16,
                                                      n_emb, n_fc, n_w2rows, n_mlp);

  int gm = (n + 127) / 128;
  float invM = 1.f / (float)n;

  // embedding -> xs16[:, 0:64)   (X fp32, W fp16, Y fp16)
  k_gemm<<<dim3(gm, 1), 256, 0, stream>>>(x, 64, embw16, 64, emb_b, nullptr, nullptr, nullptr, invM,
                                          xs16, 256, n, 64, 64, 4 | 64,
                                          nullptr, nullptr, nullptr, nullptr, nullptr);

  for (int l = 0; l < NL; ++l) {
    float* sbn1 = stats + l * 384;
    float* sbn2 = stats + l * 384 + 256;
    // fc: feat16 = h @ fc_w^T, fused attn logits (X fp16, W fp16, Y fp16)
    k_gemm<<<dim3(gm, 2), 256, 0, stream>>>(xs16 + 64 * l, 256, fcw16 + (size_t)l * 128 * 64, 64,
                                            nullptr, nullptr, nullptr, nullptr, invM,
                                            feat16, 128, n, 64, 128, 4 | 8 | 32 | 64,
                                            nullptr, attn_l + l * 128, attn_r + l * 128, el, er);
    k_agg<<<(n + 3) / 4, 256, 0, stream>>>(rowptr, csr16, feat16, el, er, gat_b + l * 128, g16, n);
    k_colstats16<<<512, 256, 0, stream>>>(g16, 128, 128, n, sbn1);
    k_foldw1<<<(218 + 3) / 4, 256, 0, stream>>>(ff_w1 + (size_t)l * 218 * 128, ff_b1 + l * 218,
                                                sbn1, bn1_g + l * 128, bn1_b + l * 128, invM,
                                                w1f16, b1p, 218, 128);
    // ff1: t16 = relu(g16 @ W1'^T + b1')   (X fp16, W fp16)
    k_gemm<<<dim3(gm, 4), 256, 0, stream>>>(g16, 128, w1f16, 128, b1p,
                                            nullptr, nullptr, nullptr, invM,
                                            t16, 224, n, 128, 218, 1 | 4 | 8 | 64,
                                            nullptr, nullptr, nullptr, nullptr, nullptr);
    // ff2: u = t16 @ W2^T + b2   (X fp16, W fp16 pitch 224, Y fp32, fused stats)
    k_gemm<<<dim3(gm, 1), 256, 0, stream>>>(t16, 224, w2w16 + (size_t)l * 64 * 224, 224, ff_b2 + l * 64,
                                            nullptr, nullptr, nullptr, invM,
                                            u, 64, n, 218, 64, 8 | 16 | 64,
                                            sbn2, nullptr, nullptr, nullptr, nullptr);
    k_bnapply<<<(n * 16 + 255) / 256, 256, 0, stream>>>(u, sbn2, bn2_g + l * 64, bn2_b + l * 64,
                                                        xs16 + 64 * (l + 1), n, invM);
  }

  float* smlp = stats + 1152;
  // mlp: u = xs16 @ mlp_w1^T   (X fp16, W fp16, Y fp32, fused col-stats)
  k_gemm<<<dim3(gm, 1), 256, 0, stream>>>(xs16, 256, mlpw16, 256, nullptr, nullptr, nullptr, nullptr, invM,
                                          u, 64, n, 256, 64, 8 | 16 | 64,
                                          smlp, nullptr, nullptr, nullptr, nullptr);
  k_final<<<(n + 3) / 4, 256, 0, stream>>>(u, smlp, mlp_bn_g, mlp_bn_b, mlp_w2, out, n, invM);
}